// Round 13
// baseline (1782.860 us; speedup 1.0000x reference)
//
#include <hip/hip_runtime.h>

// R12: occupancy doubling. R11 diagnosis: latency/barrier-bound at 2 waves/
// SIMD (24% occ), pinned by 128KB LDS W_hh0. Weights are L2-fit -> ALL
// weight matrices become fragment-records in d_ws (prep kernel, 6 mats);
// LDS = 18KB (h0/h1 dbuf + x tile). 512 blocks x 512 thr, 16 rows/block,
// __launch_bounds__(512,4) -> 2 blocks/CU, 4 waves/SIMD. Encoder 2 barriers/
// step (dbuf h0+h1). sigm/tanh IEEE divisions -> v_rcp_f32 (approx, ~1e-7).
// Frag formats + mappings identical to R11's proven path. FP32 output.

using s16x8 = __attribute__((ext_vector_type(8))) short;
using h16x8 = __attribute__((ext_vector_type(8))) _Float16;
using f32x4 = __attribute__((ext_vector_type(4))) float;

#define DEV static __device__ __forceinline__

DEV unsigned short f2h(float f) {
  _Float16 h = (_Float16)f;  // RNE
  return __builtin_bit_cast(unsigned short, h);
}
DEV float h2f(short h) {
  return (float)__builtin_bit_cast(_Float16, (unsigned short)h);
}
DEV float rcp_(float x) { return __builtin_amdgcn_rcpf(x); }
DEV float sigm(float v) { return rcp_(1.0f + __expf(-v)); }
DEV float tanh_(float v) {
  float e = __expf(-2.0f * fabsf(v));
  float r = (1.0f - e) * rcp_(1.0f + e);
  return v < 0.0f ? -r : r;
}
DEV f32x4 mf(s16x8 a, s16x8 b, f32x4 c) {
  return __builtin_amdgcn_mfma_f32_16x16x32_f16(
      __builtin_bit_cast(h16x8, a), __builtin_bit_cast(h16x8, b), c, 0, 0, 0);
}
DEV f32x4 splat4(float v) { f32x4 r = {v, v, v, v}; return r; }

// [16][128] fp16 buffer; 16 slots of 8 fp16 per row, XOR-swizzled.
DEV int swz(int row, int slot) { return row * 256 + (((slot ^ row) & 15) << 4); }
DEV s16x8 ldA(const char* buf, int ks, int lo, int hi) {
  return *(const s16x8*)(buf + swz(lo, ks * 4 + hi));
}
DEV void storeH(char* buf, int row, int col, unsigned short v) {
  int addr = row * 256 + ((((col >> 3) ^ row) & 15) << 4) + (col & 7) * 2;
  *(unsigned short*)(buf + addr) = v;
}
// LSTM pointwise: gates (i,f,g,o) -> update c, return fp16(h)
DEV unsigned short cellup(float gi, float gf, float gg, float go, float& c) {
  float i = sigm(gi), f = sigm(gf), g2 = tanh_(gg), o = sigm(go);
  c = f * c + i * g2;
  return f2h(o * tanh_(c));
}

// ---- d_ws layout (bytes) ----
// 6 mats x 128KB frag records: addr = m*131072 + ks*32768 + col*64 + hi*16
//   m: 0=eWih1 1=eWhh1 2=dWih1 3=dWhh1 4=eWhh0 5=dWhh0
// WX (eWih0 K=16 zero-padded to 32): @786432, addr = col*64 + hi*16 (32KB)
#define WS_WX 786432

__global__ void prep_kernel(
    const float* __restrict__ eWih0,
    const float* __restrict__ eWih1, const float* __restrict__ eWhh1,
    const float* __restrict__ dWih1, const float* __restrict__ dWhh1,
    const float* __restrict__ eWhh0, const float* __restrict__ dWhh0,
    char* __restrict__ ws) {
  int idx = blockIdx.x * 256 + threadIdx.x;
  if (idx < 49152) {  // 6 mats x 8192 fragment records
    int m = idx >> 13, r = idx & 8191;
    int col = r >> 4, ks = (r >> 2) & 3, hi = r & 3;
    const float* W;
    switch (m) {
      case 0: W = eWih1; break;
      case 1: W = eWhh1; break;
      case 2: W = dWih1; break;
      case 3: W = dWhh1; break;
      case 4: W = eWhh0; break;
      default: W = dWhh0; break;
    }
    const float* p = W + col * 128 + ks * 32 + hi * 8;
    s16x8 v;
#pragma unroll
    for (int j = 0; j < 8; ++j) v[j] = (short)f2h(p[j]);
    *(s16x8*)(ws + m * 131072 + ks * 32768 + col * 64 + hi * 16) = v;
  } else if (idx < 51200) {  // x-projection frags (K=16 -> 32 zero-pad)
    int r3 = idx - 49152;
    int col = r3 >> 2, hi = r3 & 3;
    s16x8 v;
#pragma unroll
    for (int j = 0; j < 8; ++j) v[j] = 0;
    if (hi < 2) {
      const float* p = eWih0 + col * 16 + hi * 8;
#pragma unroll
      for (int j = 0; j < 8; ++j) v[j] = (short)f2h(p[j]);
    }
    *(s16x8*)(ws + WS_WX + col * 64 + hi * 16) = v;
  }
}

__global__ __launch_bounds__(512, 4) void fused_kernel(
    const float* __restrict__ x,
    const float* __restrict__ ebih0, const float* __restrict__ ebhh0,
    const float* __restrict__ ebih1, const float* __restrict__ ebhh1,
    const float* __restrict__ dWih0,
    const float* __restrict__ dbih0, const float* __restrict__ dbhh0,
    const float* __restrict__ dbih1, const float* __restrict__ dbhh1,
    const float* __restrict__ fcW, const float* __restrict__ fcb,
    const char* __restrict__ ws, float* __restrict__ out) {
  __shared__ __align__(16) char smem[18304];
  char* h0B  = smem;                       // 2 x 4096 double buffer
  char* h1B  = smem + 8192;                // 2 x 4096 double buffer
  char* xL   = smem + 16384;               // 16 rows * 80B (K pad to 32)
  float* inpL = (float*)(smem + 17664);    // 16x2 fp32 decoder feedback
  char* fcwL = smem + 17792;               // 2x128 fp16

  const int tid = threadIdx.x;
  const int w = tid >> 6, l = tid & 63, lo = l & 15, hi = l >> 4;
  const int row0 = blockIdx.x * 16;
  const int colb = w * 16;
  const int obase = (colb + lo) * 64 + hi * 16;  // frag offset within record blk

  {  // zero h0B, h1B, xL (contiguous 17664 B = 1104 int4)
    int4 z = make_int4(0, 0, 0, 0);
    int4* p = (int4*)smem;
    for (int i = tid; i < 1104; i += 512) p[i] = z;
  }

  float b0[4], b1[4];
  s16x8 wx0[4];
#pragma unroll
  for (int g = 0; g < 4; ++g) {
    int col = g * 128 + colb + lo;
    b0[g] = ebih0[col] + ebhh0[col];
    b1[g] = ebih1[col] + ebhh1[col];
    wx0[g] = *(const s16x8*)(ws + WS_WX + g * 8192 + obase);
  }
  float c0s[4], c1s[4];
#pragma unroll
  for (int r = 0; r < 4; ++r) { c0s[r] = 0.f; c1s[r] = 0.f; }

  const int xr = tid >> 4, xf = tid & 15;
  const float* xrow = x + (long long)(row0 + xr) * 1600 + xf;
  float xv = (tid < 256) ? xrow[0] : 0.f;
  int cur = 0;

  // ================= encoder (T=100) =================
  for (int t = 0; t < 100; ++t) {
    if (tid < 256) *(unsigned short*)(xL + xr * 80 + xf * 2) = f2h(xv);
    __syncthreads();  // B1: xL + prev h1 writes visible
    if (t < 99 && tid < 256) xv = xrow[(t + 1) * 16];  // prefetch

    char* h0r = h0B + cur * 4096;
    char* h0w = h0B + (cur ^ 1) * 4096;
    char* h1r = h1B + cur * 4096;
    char* h1w = h1B + (cur ^ 1) * 4096;

    // ---- layer 0: g = x@Wih0^T + h0@Whh0^T + b0 (W_hh0 frags: mat 4)
    f32x4 acc[4];
#pragma unroll
    for (int g = 0; g < 4; ++g) acc[g] = splat4(b0[g]);
    {
      s16x8 ax = *(const s16x8*)(xL + lo * 80 + hi * 16);
#pragma unroll
      for (int g = 0; g < 4; ++g) acc[g] = mf(ax, wx0[g], acc[g]);
    }
    int lf0 = 0;
    asm("" : "+s"(lf0));  // defeat LICM (no 64-reg hoist)
    const char* W0 = ws + 4 * 131072 + lf0;
#pragma unroll
    for (int ks = 0; ks < 4; ++ks) {
      s16x8 a0 = ldA(h0r, ks, lo, hi);
      const char* wk = W0 + ks * 32768 + obase;
#pragma unroll
      for (int g = 0; g < 4; ++g) {
        s16x8 bb = *(const s16x8*)(wk + g * 8192);
        acc[g] = mf(a0, bb, acc[g]);
      }
    }
    unsigned short hb[4];
#pragma unroll
    for (int r = 0; r < 4; ++r)
      hb[r] = cellup(acc[0][r], acc[1][r], acc[2][r], acc[3][r], c0s[r]);
#pragma unroll
    for (int r = 0; r < 4; ++r) storeH(h0w, hi * 4 + r, colb + lo, hb[r]);
    __syncthreads();  // B2: h0-new visible

    // ---- layer 1: g = h0new@Wih1^T + h1@Whh1^T + b1 (mats 0/1)
#pragma unroll
    for (int g = 0; g < 4; ++g) acc[g] = splat4(b1[g]);
    int lf1 = 0;
    asm("" : "+s"(lf1));
    const char* W1 = ws + lf1;
#pragma unroll
    for (int s = 0; s < 8; ++s) {
      const char* src = (s < 4) ? h0w : h1r;
      int ks = s & 3;
      const char* wk = W1 + (s < 4 ? 0 : 131072) + ks * 32768 + obase;
      s16x8 a0 = ldA(src, ks, lo, hi);
#pragma unroll
      for (int g = 0; g < 4; ++g) {
        s16x8 bb = *(const s16x8*)(wk + g * 8192);
        acc[g] = mf(a0, bb, acc[g]);
      }
    }
#pragma unroll
    for (int r = 0; r < 4; ++r)
      hb[r] = cellup(acc[0][r], acc[1][r], acc[2][r], acc[3][r], c1s[r]);
#pragma unroll
    for (int r = 0; r < 4; ++r) storeH(h1w, hi * 4 + r, colb + lo, hb[r]);
    cur ^= 1;  // h1w visibility covered by next step's B1
  }

  // ================= restage for decoder =================
  float dwx[4][2];
#pragma unroll
  for (int g = 0; g < 4; ++g) {
    int col = g * 128 + colb + lo;
    b0[g] = dbih0[col] + dbhh0[col];
    b1[g] = dbih1[col] + dbhh1[col];
    dwx[g][0] = dWih0[col * 2 + 0];
    dwx[g][1] = dWih0[col * 2 + 1];
  }
  if (tid < 32) {  // dec_in = x[:, 99, :2] (fp32)
    int r = tid >> 1, o = tid & 1;
    inpL[r * 2 + o] = x[(long long)(row0 + r) * 1600 + 1584 + o];
  }
  if (tid < 256) {
    int o = tid >> 7, k = tid & 127;
    *(unsigned short*)(fcwL + o * 256 + k * 2) = f2h(fcW[o * 128 + k]);
  }
  float fb0 = fcb[0], fb1 = fcb[1];
  __syncthreads();  // decoder inputs + final h states visible

  // ================= decoder (TGT=60) =================
  for (int t = 0; t < 60; ++t) {
    char* h0r = h0B + cur * 4096;
    char* h0w = h0B + (cur ^ 1) * 4096;
    char* h1r = h1B + cur * 4096;
    char* h1w = h1B + (cur ^ 1) * 4096;

    // ---- layer 0: g = inp@dWih0^T (VALU, K=2) + h0@dWhh0^T (mat 5) + b0
    f32x4 acc[4];
#pragma unroll
    for (int r = 0; r < 4; ++r) {
      float2 ip = *(const float2*)(inpL + (hi * 4 + r) * 2);
#pragma unroll
      for (int g = 0; g < 4; ++g)
        acc[g][r] = b0[g] + ip.x * dwx[g][0] + ip.y * dwx[g][1];
    }
    int lf0 = 0;
    asm("" : "+s"(lf0));
    const char* W0 = ws + 5 * 131072 + lf0;
#pragma unroll
    for (int ks = 0; ks < 4; ++ks) {
      s16x8 a0 = ldA(h0r, ks, lo, hi);
      const char* wk = W0 + ks * 32768 + obase;
#pragma unroll
      for (int g = 0; g < 4; ++g) {
        s16x8 bb = *(const s16x8*)(wk + g * 8192);
        acc[g] = mf(a0, bb, acc[g]);
      }
    }
    unsigned short hb[4];
#pragma unroll
    for (int r = 0; r < 4; ++r)
      hb[r] = cellup(acc[0][r], acc[1][r], acc[2][r], acc[3][r], c0s[r]);
#pragma unroll
    for (int r = 0; r < 4; ++r) storeH(h0w, hi * 4 + r, colb + lo, hb[r]);
    __syncthreads();  // B2: h0-new visible

    // ---- layer 1 (mats 2/3)
#pragma unroll
    for (int g = 0; g < 4; ++g) acc[g] = splat4(b1[g]);
    int lf1 = 0;
    asm("" : "+s"(lf1));
    const char* W1 = ws + 2 * 131072 + lf1;
#pragma unroll
    for (int s = 0; s < 8; ++s) {
      const char* src = (s < 4) ? h0w : h1r;
      int ks = s & 3;
      const char* wk = W1 + (s < 4 ? 0 : 131072) + ks * 32768 + obase;
      s16x8 a0 = ldA(src, ks, lo, hi);
#pragma unroll
      for (int g = 0; g < 4; ++g) {
        s16x8 bb = *(const s16x8*)(wk + g * 8192);
        acc[g] = mf(a0, bb, acc[g]);
      }
    }
#pragma unroll
    for (int r = 0; r < 4; ++r)
      hb[r] = cellup(acc[0][r], acc[1][r], acc[2][r], acc[3][r], c1s[r]);
#pragma unroll
    for (int r = 0; r < 4; ++r) storeH(h1w, hi * 4 + r, colb + lo, hb[r]);
    __syncthreads();  // B3: h1-new visible for FC

    // ---- FC head + feedback (wave 0: lane -> (row=lo, o, kh))
    if (w == 0) {
      int o = hi & 1, kh = hi >> 1;
      float sum = 0.f;
#pragma unroll
      for (int cc = 0; cc < 8; ++cc) {
        s16x8 hv = *(const s16x8*)(h1w + swz(lo, kh * 8 + cc));
        s16x8 wv = *(const s16x8*)(fcwL + o * 256 + (kh * 8 + cc) * 16);
#pragma unroll
        for (int j = 0; j < 8; ++j) sum += h2f(hv[j]) * h2f(wv[j]);
      }
      sum += __shfl_xor(sum, 32, 64);
      if (l < 32) {
        float ov = sum + (o ? fb1 : fb0);
        inpL[lo * 2 + o] = ov;  // fp32 feedback, matches reference carry
        out[((long long)(row0 + lo) * 60 + t) * 2 + o] = ov;
      }
    }
    __syncthreads();  // B1(end): inpL visible for next step's layer 0
    cur ^= 1;
  }
}

extern "C" void kernel_launch(void* const* d_in, const int* in_sizes, int n_in,
                              void* d_out, int out_size, void* d_ws, size_t ws_size,
                              hipStream_t stream) {
  (void)in_sizes; (void)n_in; (void)out_size; (void)ws_size;
  const float* x      = (const float*)d_in[0];
  // d_in[1] = target_len (60), hardcoded
  const float* eWih0  = (const float*)d_in[2];
  const float* eWhh0  = (const float*)d_in[3];
  const float* ebih0  = (const float*)d_in[4];
  const float* ebhh0  = (const float*)d_in[5];
  const float* eWih1  = (const float*)d_in[6];
  const float* eWhh1  = (const float*)d_in[7];
  const float* ebih1  = (const float*)d_in[8];
  const float* ebhh1  = (const float*)d_in[9];
  const float* dWih0  = (const float*)d_in[10];
  const float* dWhh0  = (const float*)d_in[11];
  const float* dbih0  = (const float*)d_in[12];
  const float* dbhh0  = (const float*)d_in[13];
  const float* dWih1  = (const float*)d_in[14];
  const float* dWhh1  = (const float*)d_in[15];
  const float* dbih1  = (const float*)d_in[16];
  const float* dbhh1  = (const float*)d_in[17];
  const float* fcW    = (const float*)d_in[18];
  const float* fcb    = (const float*)d_in[19];
  float* out          = (float*)d_out;
  char* ws            = (char*)d_ws;

  prep_kernel<<<200, 256, 0, stream>>>(eWih0, eWih1, eWhh1, dWih1, dWhh1,
                                       eWhh0, dWhh0, ws);

  fused_kernel<<<512, 512, 0, stream>>>(
      x, ebih0, ebhh0, ebih1, ebhh1, dWih0, dbih0, dbhh0, dbih1, dbhh1,
      fcW, fcb, ws, out);
}

// Round 14
// 1188.830 us; speedup vs baseline: 1.4997x; 1.4997x over previous
//
#include <hip/hip_runtime.h>

// R13: stall-structure attack on R11 (1.51ms). Geometry unchanged (256 blocks
// x 512 thr, 32 rows/block, 1 block/CU). Changes:
//  1. FUSED encoder phase: layer1(t) & layer0(t+1) are independent given
//     h0(t) -> one barrier/step (was 3). h0/h1/x all double-buffered.
//  2. Decoder FC-FOLD: inp(t+1)=FC(h1(t)) enters L0 only via dWih0 (K=2) ->
//     Wcomb = dWih0 @ fcW prep'd as mat 6; decoder L0 = h0@dWhh0 + h1@Wcomb.
//     FC head only produces output (off the recurrence), 2 barriers/step.
//  3. rcp-based sigm/tanh kept from R12 (VALUBusy 57->31 evidence).
//  4. W_hh0: gates i,f,g as swizzled LDS image (96KB); gate o via L2 frags.
// All frag-record/image/MFMA mappings are the R11/R12-proven ones.

using s16x8 = __attribute__((ext_vector_type(8))) short;
using h16x8 = __attribute__((ext_vector_type(8))) _Float16;
using f32x4 = __attribute__((ext_vector_type(4))) float;

#define DEV static __device__ __forceinline__

DEV unsigned short f2h(float f) {
  _Float16 h = (_Float16)f;  // RNE
  return __builtin_bit_cast(unsigned short, h);
}
DEV float h2f(short h) {
  return (float)__builtin_bit_cast(_Float16, (unsigned short)h);
}
DEV float rcp_(float x) { return __builtin_amdgcn_rcpf(x); }
DEV float sigm(float v) { return rcp_(1.0f + __expf(-v)); }
DEV float tanh_(float v) {
  float e = __expf(-2.0f * fabsf(v));
  float r = (1.0f - e) * rcp_(1.0f + e);
  return v < 0.0f ? -r : r;
}
DEV f32x4 mf(s16x8 a, s16x8 b, f32x4 c) {
  return __builtin_amdgcn_mfma_f32_16x16x32_f16(
      __builtin_bit_cast(h16x8, a), __builtin_bit_cast(h16x8, b), c, 0, 0, 0);
}
DEV f32x4 splat4(float v) { f32x4 r = {v, v, v, v}; return r; }

// [rows][128] fp16 buffer; 16 slots of 8 fp16 per row, XOR-swizzled.
DEV int swz(int row, int slot) { return row * 256 + (((slot ^ row) & 15) << 4); }
DEV s16x8 ldA(const char* buf, int rt, int ks, int lo, int hi) {
  return *(const s16x8*)(buf + swz(rt * 16 + lo, ks * 4 + hi));
}
DEV s16x8 ldB(const char* wlds, int colbase, int ks, int lo, int hi) {
  return *(const s16x8*)(wlds + swz(colbase + lo, ks * 4 + hi));
}
DEV void storeH(char* buf, int row, int col, unsigned short v) {
  int addr = row * 256 + ((((col >> 3) ^ row) & 15) << 4) + (col & 7) * 2;
  *(unsigned short*)(buf + addr) = v;
}
DEV unsigned short cellup(float gi, float gf, float gg, float go, float& c) {
  float i = sigm(gi), f = sigm(gf), g2 = tanh_(gg), o = sigm(go);
  c = f * c + i * g2;
  return f2h(o * tanh_(c));
}

// ---- d_ws layout (bytes) ----
// frag records, mats m*131072, addr = m*131072 + ks*32768 + col*64 + hi*16
//   m: 0=eWih1 1=eWhh1 2=dWih1 3=dWhh1 4=eWhh0 5=dWhh0 6=Wcomb(dWih0@fcW)
// WX (eWih0 K=16 zero-pad-32 frags) @917504 (32KB)
// IMG_E (eWhh0 rows 0..383 swizzled) @950272 (96KB)
// IMG_D (dWhh0 rows 0..383 swizzled) @1048576 (96KB)
#define WS_WX  917504
#define WS_IME 950272
#define WS_IMD 1048576

__global__ void prep_kernel(
    const float* __restrict__ eWih0, const float* __restrict__ eWhh0,
    const float* __restrict__ eWih1, const float* __restrict__ eWhh1,
    const float* __restrict__ dWih0, const float* __restrict__ dWhh0,
    const float* __restrict__ dWih1, const float* __restrict__ dWhh1,
    const float* __restrict__ fcW, char* __restrict__ ws) {
  int idx = blockIdx.x * 256 + threadIdx.x;
  if (idx < 57344) {  // 7 mats x 8192 fragment records
    int m = idx >> 13, r = idx & 8191;
    int col = r >> 4, ks = (r >> 2) & 3, hi = r & 3;
    s16x8 v;
    if (m == 6) {  // Wcomb[col][k] = dWih0[col][0]*fcW[0][k]+dWih0[col][1]*fcW[1][k]
      float w0 = dWih0[col * 2 + 0], w1 = dWih0[col * 2 + 1];
#pragma unroll
      for (int j = 0; j < 8; ++j) {
        int k = ks * 32 + hi * 8 + j;
        v[j] = (short)f2h(w0 * fcW[k] + w1 * fcW[128 + k]);
      }
    } else {
      const float* W;
      switch (m) {
        case 0: W = eWih1; break;
        case 1: W = eWhh1; break;
        case 2: W = dWih1; break;
        case 3: W = dWhh1; break;
        case 4: W = eWhh0; break;
        default: W = dWhh0; break;
      }
      const float* p = W + col * 128 + ks * 32 + hi * 8;
#pragma unroll
      for (int j = 0; j < 8; ++j) v[j] = (short)f2h(p[j]);
    }
    *(s16x8*)(ws + m * 131072 + ks * 32768 + col * 64 + hi * 16) = v;
  } else if (idx < 59392) {  // WX frags
    int r3 = idx - 57344;
    int col = r3 >> 2, hi = r3 & 3;
    s16x8 v;
#pragma unroll
    for (int j = 0; j < 8; ++j) v[j] = 0;
    if (hi < 2) {
      const float* p = eWih0 + col * 16 + hi * 8;
#pragma unroll
      for (int j = 0; j < 8; ++j) v[j] = (short)f2h(p[j]);
    }
    *(s16x8*)(ws + WS_WX + col * 64 + hi * 16) = v;
  } else if (idx < 71680) {  // swizzled 3-gate images (rows 0..383)
    int r2 = idx - 59392;
    int m = (r2 >= 6144), rr = m ? r2 - 6144 : r2;
    int row = rr >> 4, s = rr & 15;
    const float* p = (m ? dWhh0 : eWhh0) + row * 128 + s * 8;
    s16x8 v;
#pragma unroll
    for (int j = 0; j < 8; ++j) v[j] = (short)f2h(p[j]);
    *(s16x8*)(ws + (m ? WS_IMD : WS_IME) + row * 256 + (((s ^ row) & 15) << 4)) = v;
  }
}

#define SMEM_BYTES 136960

__global__ __launch_bounds__(512, 2) void fused_kernel(
    const float* __restrict__ x,
    const float* __restrict__ ebih0, const float* __restrict__ ebhh0,
    const float* __restrict__ ebih1, const float* __restrict__ ebhh1,
    const float* __restrict__ dWih0,
    const float* __restrict__ dbih0, const float* __restrict__ dbhh0,
    const float* __restrict__ dbih1, const float* __restrict__ dbhh1,
    const float* __restrict__ fcW, const float* __restrict__ fcb,
    const char* __restrict__ ws, float* __restrict__ out) {
  extern __shared__ char smem[];
  char* wL   = smem;                       // 98304: 3-gate W_hh0 image
  char* h0B  = smem + 98304;               // 2 x 8192
  char* h1B  = smem + 114688;              // 2 x 8192
  char* xB   = smem + 131072;              // 2 x 2560
  float* inpL = (float*)(smem + 136192);   // 32x2 fp32 (decoder t=0 input)
  char* fcwL = smem + 136448;              // 2x128 fp16

  const int tid = threadIdx.x;
  const int w = tid >> 6, l = tid & 63, lo = l & 15, hi = l >> 4;
  const int row0 = blockIdx.x * 32;
  const int colb = w * 16;
  const int obase = (colb + lo) * 64 + hi * 16;   // frag offset, gate 0
  const int obase3 = obase + 384 * 64;            // gate 3

  // ================= init =================
  {  // stage IMG_E -> wL
    const int4* src = (const int4*)(ws + WS_IME);
    int4* dst = (int4*)wL;
    for (int i = tid; i < 6144; i += 512) dst[i] = src[i];
  }
  {  // zero h0B,h1B,xB (37888 B contiguous from h0B)
    int4 z = make_int4(0, 0, 0, 0);
    int4* p = (int4*)h0B;
    for (int i = tid; i < 2368; i += 512) p[i] = z;
  }

  float b0[4], b1[4];
  s16x8 wx0[4];
#pragma unroll
  for (int g = 0; g < 4; ++g) {
    int col = g * 128 + colb + lo;
    b0[g] = ebih0[col] + ebhh0[col];
    b1[g] = ebih1[col] + ebhh1[col];
    wx0[g] = *(const s16x8*)(ws + WS_WX + g * 8192 + obase);
  }
  float c0s[2][4], c1s[2][4];
#pragma unroll
  for (int rt = 0; rt < 2; ++rt)
#pragma unroll
    for (int r = 0; r < 4; ++r) { c0s[rt][r] = 0.f; c1s[rt][r] = 0.f; }

  const int xr = tid >> 4, xf = tid & 15;
  const float* xrow = x + (long long)(row0 + xr) * 1600 + xf;
  // stage x_0 into xB[0]
  *(unsigned short*)(xB + xr * 80 + xf * 2) = f2h(xrow[0]);
  float xv = xrow[16];  // x_1
  int cur = 0;
  __syncthreads();

  // ================= encoder: 101 fused phases, 1 barrier each ============
  for (int k = 0; k <= 100; ++k) {
    char* h0r = h0B + cur * 8192;
    char* h0w = h0B + (cur ^ 1) * 8192;
    char* h1r = h1B + cur * 8192;
    char* h1w = h1B + (cur ^ 1) * 8192;
    char* xc  = xB + cur * 2560;
    char* xn  = xB + (cur ^ 1) * 2560;

    float xv_stage = xv;                       // x_{k+1}
    if (k < 98) xv = xrow[(k + 2) * 16];       // issue prefetch early

    if (k > 0) {  // ---- layer 1: h1(k) = cell1(h0(k), h1(k-1))
      f32x4 acc[2][4];
#pragma unroll
      for (int g = 0; g < 4; ++g) { acc[0][g] = splat4(b1[g]); acc[1][g] = splat4(b1[g]); }
      int lf = 0;
      asm("" : "+s"(lf));  // defeat LICM
      const char* W1 = ws + lf;  // mats 0/1
#pragma unroll
      for (int s = 0; s < 8; ++s) {
        const char* src = (s < 4) ? h0r : h1r;
        int ks = s & 3;
        const char* wk = W1 + (s < 4 ? 0 : 131072) + ks * 32768 + obase;
        s16x8 a0 = ldA(src, 0, ks, lo, hi), a1 = ldA(src, 1, ks, lo, hi);
#pragma unroll
        for (int g = 0; g < 4; ++g) {
          s16x8 bb = *(const s16x8*)(wk + g * 8192);
          acc[0][g] = mf(a0, bb, acc[0][g]);
          acc[1][g] = mf(a1, bb, acc[1][g]);
        }
      }
#pragma unroll
      for (int rt = 0; rt < 2; ++rt)
#pragma unroll
        for (int r = 0; r < 4; ++r)
          storeH(h1w, rt * 16 + hi * 4 + r, colb + lo,
                 cellup(acc[rt][0][r], acc[rt][1][r], acc[rt][2][r], acc[rt][3][r], c1s[rt][r]));
    }

    __builtin_amdgcn_sched_barrier(0x30);  // only VMEM may cross (prefetch)

    if (k < 100) {  // ---- layer 0: h0(k+1) = cell0(x_k, h0(k))
      f32x4 acc[2][4];
#pragma unroll
      for (int g = 0; g < 4; ++g) { acc[0][g] = splat4(b0[g]); acc[1][g] = splat4(b0[g]); }
      {
        s16x8 a0 = *(const s16x8*)(xc + lo * 80 + hi * 16);
        s16x8 a1 = *(const s16x8*)(xc + (16 + lo) * 80 + hi * 16);
#pragma unroll
        for (int g = 0; g < 4; ++g) {
          acc[0][g] = mf(a0, wx0[g], acc[0][g]);
          acc[1][g] = mf(a1, wx0[g], acc[1][g]);
        }
      }
      int lf = 0;
      asm("" : "+s"(lf));
      const char* W0 = ws + 4 * 131072 + lf;  // eWhh0 records (gate 3)
#pragma unroll
      for (int ks = 0; ks < 4; ++ks) {
        s16x8 a0 = ldA(h0r, 0, ks, lo, hi), a1 = ldA(h0r, 1, ks, lo, hi);
#pragma unroll
        for (int g = 0; g < 3; ++g) {
          s16x8 bb = ldB(wL, g * 128 + colb, ks, lo, hi);
          acc[0][g] = mf(a0, bb, acc[0][g]);
          acc[1][g] = mf(a1, bb, acc[1][g]);
        }
        s16x8 b3 = *(const s16x8*)(W0 + ks * 32768 + obase3);
        acc[0][3] = mf(a0, b3, acc[0][3]);
        acc[1][3] = mf(a1, b3, acc[1][3]);
      }
#pragma unroll
      for (int rt = 0; rt < 2; ++rt)
#pragma unroll
        for (int r = 0; r < 4; ++r)
          storeH(h0w, rt * 16 + hi * 4 + r, colb + lo,
                 cellup(acc[rt][0][r], acc[rt][1][r], acc[rt][2][r], acc[rt][3][r], c0s[rt][r]));
      if (k < 99)  // stage x_{k+1} for next phase
        *(unsigned short*)(xn + xr * 80 + xf * 2) = f2h(xv_stage);
    }
    __syncthreads();
    cur ^= 1;
  }
  // final states: h0(100) in h0B[cur^1], h1(100) in h1B[cur]
  int dc0 = cur ^ 1, dc1 = cur;

  // ================= restage for decoder =================
  {  // IMG_D -> wL (safe: k=100 phase used no wL)
    const int4* src = (const int4*)(ws + WS_IMD);
    int4* dst = (int4*)wL;
    for (int i = tid; i < 6144; i += 512) dst[i] = src[i];
  }
  if (tid < 64) {  // dec_in = x[:, 99, :2]
    int r = tid >> 1, o = tid & 1;
    inpL[r * 2 + o] = x[(long long)(row0 + r) * 1600 + 1584 + o];
  }
  if (tid < 256) {
    int o = tid >> 7, k2 = tid & 127;
    *(unsigned short*)(fcwL + o * 256 + k2 * 2) = f2h(fcW[o * 128 + k2]);
  }
  float dwx[4][2], b0f[4];
#pragma unroll
  for (int g = 0; g < 4; ++g) {
    int col = g * 128 + colb + lo;
    b0[g] = dbih0[col] + dbhh0[col];
    b1[g] = dbih1[col] + dbhh1[col];
    dwx[g][0] = dWih0[col * 2 + 0];
    dwx[g][1] = dWih0[col * 2 + 1];
  }
  float fb0 = fcb[0], fb1 = fcb[1];
#pragma unroll
  for (int g = 0; g < 4; ++g) b0f[g] = b0[g] + dwx[g][0] * fb0 + dwx[g][1] * fb1;
  __syncthreads();

  // ================= decoder =================
  // Phase A0 (t=0): h0^1 = cell0(inp0 [VALU], h0^0 @ dWhh0)
  {
    f32x4 acc[2][4];
    char* h0r = h0B + dc0 * 8192;
    char* h0w = h0B + (dc0 ^ 1) * 8192;
#pragma unroll
    for (int rt = 0; rt < 2; ++rt)
#pragma unroll
      for (int r = 0; r < 4; ++r) {
        float2 ip = *(const float2*)(inpL + (rt * 16 + hi * 4 + r) * 2);
#pragma unroll
        for (int g = 0; g < 4; ++g)
          acc[rt][g][r] = b0[g] + ip.x * dwx[g][0] + ip.y * dwx[g][1];
      }
    int lf = 0;
    asm("" : "+s"(lf));
    const char* WA = ws + 5 * 131072 + lf;  // dWhh0 records (gate 3)
#pragma unroll
    for (int ks = 0; ks < 4; ++ks) {
      s16x8 a0 = ldA(h0r, 0, ks, lo, hi), a1 = ldA(h0r, 1, ks, lo, hi);
#pragma unroll
      for (int g = 0; g < 3; ++g) {
        s16x8 bb = ldB(wL, g * 128 + colb, ks, lo, hi);
        acc[0][g] = mf(a0, bb, acc[0][g]);
        acc[1][g] = mf(a1, bb, acc[1][g]);
      }
      s16x8 b3 = *(const s16x8*)(WA + ks * 32768 + obase3);
      acc[0][3] = mf(a0, b3, acc[0][3]);
      acc[1][3] = mf(a1, b3, acc[1][3]);
    }
#pragma unroll
    for (int rt = 0; rt < 2; ++rt)
#pragma unroll
      for (int r = 0; r < 4; ++r)
        storeH(h0w, rt * 16 + hi * 4 + r, colb + lo,
               cellup(acc[rt][0][r], acc[rt][1][r], acc[rt][2][r], acc[rt][3][r], c0s[rt][r]));
    dc0 ^= 1;
    __syncthreads();
  }

  for (int t = 0; t < 60; ++t) {
    // ---- Phase B(t): h1^{t+1} = cell1(h0^{t+1} @ dWih1 + h1^t @ dWhh1)
    {
      char* h0r = h0B + dc0 * 8192;
      char* h1r = h1B + dc1 * 8192;
      char* h1w = h1B + (dc1 ^ 1) * 8192;
      f32x4 acc[2][4];
#pragma unroll
      for (int g = 0; g < 4; ++g) { acc[0][g] = splat4(b1[g]); acc[1][g] = splat4(b1[g]); }
      int lf = 0;
      asm("" : "+s"(lf));
      const char* WB = ws + 2 * 131072 + lf;  // mats 2/3
#pragma unroll
      for (int s = 0; s < 8; ++s) {
        const char* src = (s < 4) ? h0r : h1r;
        int ks = s & 3;
        const char* wk = WB + (s < 4 ? 0 : 131072) + ks * 32768 + obase;
        s16x8 a0 = ldA(src, 0, ks, lo, hi), a1 = ldA(src, 1, ks, lo, hi);
#pragma unroll
        for (int g = 0; g < 4; ++g) {
          s16x8 bb = *(const s16x8*)(wk + g * 8192);
          acc[0][g] = mf(a0, bb, acc[0][g]);
          acc[1][g] = mf(a1, bb, acc[1][g]);
        }
      }
#pragma unroll
      for (int rt = 0; rt < 2; ++rt)
#pragma unroll
        for (int r = 0; r < 4; ++r)
          storeH(h1w, rt * 16 + hi * 4 + r, colb + lo,
                 cellup(acc[rt][0][r], acc[rt][1][r], acc[rt][2][r], acc[rt][3][r], c1s[rt][r]));
      dc1 ^= 1;
      __syncthreads();
    }

    // ---- Phase A(t+1): h0^{t+2} = cell0'(h1^{t+1} @ Wcomb + h0^{t+1} @ dWhh0)
    //      + FC output out(t) = FC(h1^{t+1})  (waves 0,1)
    {
      char* h1r = h1B + dc1 * 8192;   // h1^{t+1}
      if (w < 2) {
        int row = w * 16 + lo;
        int o = hi & 1, kh = hi >> 1;
        float sum = 0.f;
#pragma unroll
        for (int cc = 0; cc < 8; ++cc) {
          s16x8 hv = *(const s16x8*)(h1r + swz(row, kh * 8 + cc));
          s16x8 wv = *(const s16x8*)(fcwL + o * 256 + (kh * 8 + cc) * 16);
#pragma unroll
          for (int j = 0; j < 8; ++j) sum += h2f(hv[j]) * h2f(wv[j]);
        }
        sum += __shfl_xor(sum, 32, 64);
        if (l < 32)
          out[((long long)(row0 + row) * 60 + t) * 2 + o] = sum + (o ? fb1 : fb0);
      }
      if (t < 59) {
        char* h0r = h0B + dc0 * 8192;
        char* h0w = h0B + (dc0 ^ 1) * 8192;
        f32x4 acc[2][4];
#pragma unroll
        for (int g = 0; g < 4; ++g) { acc[0][g] = splat4(b0f[g]); acc[1][g] = splat4(b0f[g]); }
        int lf = 0;
        asm("" : "+s"(lf));
        const char* WA = ws + 5 * 131072 + lf;   // dWhh0 gate-3 records
        const char* WC = ws + 6 * 131072 + lf;   // Wcomb records
#pragma unroll
        for (int ks = 0; ks < 4; ++ks) {
          s16x8 a0 = ldA(h0r, 0, ks, lo, hi), a1 = ldA(h0r, 1, ks, lo, hi);
          s16x8 e0 = ldA(h1r, 0, ks, lo, hi), e1 = ldA(h1r, 1, ks, lo, hi);
#pragma unroll
          for (int g = 0; g < 3; ++g) {
            s16x8 bb = ldB(wL, g * 128 + colb, ks, lo, hi);
            acc[0][g] = mf(a0, bb, acc[0][g]);
            acc[1][g] = mf(a1, bb, acc[1][g]);
          }
          s16x8 b3 = *(const s16x8*)(WA + ks * 32768 + obase3);
          acc[0][3] = mf(a0, b3, acc[0][3]);
          acc[1][3] = mf(a1, b3, acc[1][3]);
#pragma unroll
          for (int g = 0; g < 4; ++g) {
            s16x8 bc = *(const s16x8*)(WC + ks * 32768 + g * 8192 + obase);
            acc[0][g] = mf(e0, bc, acc[0][g]);
            acc[1][g] = mf(e1, bc, acc[1][g]);
          }
        }
#pragma unroll
        for (int rt = 0; rt < 2; ++rt)
#pragma unroll
          for (int r = 0; r < 4; ++r)
            storeH(h0w, rt * 16 + hi * 4 + r, colb + lo,
                   cellup(acc[rt][0][r], acc[rt][1][r], acc[rt][2][r], acc[rt][3][r], c0s[rt][r]));
        dc0 ^= 1;
      }
      __syncthreads();
    }
  }
}

extern "C" void kernel_launch(void* const* d_in, const int* in_sizes, int n_in,
                              void* d_out, int out_size, void* d_ws, size_t ws_size,
                              hipStream_t stream) {
  (void)in_sizes; (void)n_in; (void)out_size; (void)ws_size;
  const float* x      = (const float*)d_in[0];
  // d_in[1] = target_len (60), hardcoded
  const float* eWih0  = (const float*)d_in[2];
  const float* eWhh0  = (const float*)d_in[3];
  const float* ebih0  = (const float*)d_in[4];
  const float* ebhh0  = (const float*)d_in[5];
  const float* eWih1  = (const float*)d_in[6];
  const float* eWhh1  = (const float*)d_in[7];
  const float* ebih1  = (const float*)d_in[8];
  const float* ebhh1  = (const float*)d_in[9];
  const float* dWih0  = (const float*)d_in[10];
  const float* dWhh0  = (const float*)d_in[11];
  const float* dbih0  = (const float*)d_in[12];
  const float* dbhh0  = (const float*)d_in[13];
  const float* dWih1  = (const float*)d_in[14];
  const float* dWhh1  = (const float*)d_in[15];
  const float* dbih1  = (const float*)d_in[16];
  const float* dbhh1  = (const float*)d_in[17];
  const float* fcW    = (const float*)d_in[18];
  const float* fcb    = (const float*)d_in[19];
  float* out          = (float*)d_out;
  char* ws            = (char*)d_ws;

  prep_kernel<<<280, 256, 0, stream>>>(eWih0, eWhh0, eWih1, eWhh1,
                                       dWih0, dWhh0, dWih1, dWhh1, fcW, ws);

  hipFuncSetAttribute(reinterpret_cast<const void*>(fused_kernel),
                      hipFuncAttributeMaxDynamicSharedMemorySize, SMEM_BYTES);

  fused_kernel<<<256, 512, SMEM_BYTES, stream>>>(
      x, ebih0, ebhh0, ebih1, ebhh1, dWih0, dbih0, dbhh0, dbih1, dbhh1,
      fcW, fcb, ws, out);
}

// Round 15
// 1183.910 us; speedup vs baseline: 1.5059x; 1.0042x over previous
//
#include <hip/hip_runtime.h>

// R13: stall-structure attack on R11 (1.51ms). Geometry unchanged (256 blocks
// x 512 thr, 32 rows/block, 1 block/CU). Changes:
//  1. FUSED encoder phase: layer1(t) & layer0(t+1) are independent given
//     h0(t) -> one barrier/step (was 3). h0/h1/x all double-buffered.
//  2. Decoder FC-FOLD: inp(t+1)=FC(h1(t)) enters L0 only via dWih0 (K=2) ->
//     Wcomb = dWih0 @ fcW prep'd as mat 6; decoder L0 = h0@dWhh0 + h1@Wcomb.
//     FC head only produces output (off the recurrence), 2 barriers/step.
//  3. rcp-based sigm/tanh kept from R12 (VALUBusy 57->31 evidence).
//  4. W_hh0: gates i,f,g as swizzled LDS image (96KB); gate o via L2 frags.
// All frag-record/image/MFMA mappings are the R11/R12-proven ones.

using s16x8 = __attribute__((ext_vector_type(8))) short;
using h16x8 = __attribute__((ext_vector_type(8))) _Float16;
using f32x4 = __attribute__((ext_vector_type(4))) float;

#define DEV static __device__ __forceinline__

DEV unsigned short f2h(float f) {
  _Float16 h = (_Float16)f;  // RNE
  return __builtin_bit_cast(unsigned short, h);
}
DEV float h2f(short h) {
  return (float)__builtin_bit_cast(_Float16, (unsigned short)h);
}
DEV float rcp_(float x) { return __builtin_amdgcn_rcpf(x); }
DEV float sigm(float v) { return rcp_(1.0f + __expf(-v)); }
DEV float tanh_(float v) {
  float e = __expf(-2.0f * fabsf(v));
  float r = (1.0f - e) * rcp_(1.0f + e);
  return v < 0.0f ? -r : r;
}
DEV f32x4 mf(s16x8 a, s16x8 b, f32x4 c) {
  return __builtin_amdgcn_mfma_f32_16x16x32_f16(
      __builtin_bit_cast(h16x8, a), __builtin_bit_cast(h16x8, b), c, 0, 0, 0);
}
DEV f32x4 splat4(float v) { f32x4 r = {v, v, v, v}; return r; }

// [rows][128] fp16 buffer; 16 slots of 8 fp16 per row, XOR-swizzled.
DEV int swz(int row, int slot) { return row * 256 + (((slot ^ row) & 15) << 4); }
DEV s16x8 ldA(const char* buf, int rt, int ks, int lo, int hi) {
  return *(const s16x8*)(buf + swz(rt * 16 + lo, ks * 4 + hi));
}
DEV s16x8 ldB(const char* wlds, int colbase, int ks, int lo, int hi) {
  return *(const s16x8*)(wlds + swz(colbase + lo, ks * 4 + hi));
}
DEV void storeH(char* buf, int row, int col, unsigned short v) {
  int addr = row * 256 + ((((col >> 3) ^ row) & 15) << 4) + (col & 7) * 2;
  *(unsigned short*)(buf + addr) = v;
}
DEV unsigned short cellup(float gi, float gf, float gg, float go, float& c) {
  float i = sigm(gi), f = sigm(gf), g2 = tanh_(gg), o = sigm(go);
  c = f * c + i * g2;
  return f2h(o * tanh_(c));
}

// ---- d_ws layout (bytes) ----
// frag records, mats m*131072, addr = m*131072 + ks*32768 + col*64 + hi*16
//   m: 0=eWih1 1=eWhh1 2=dWih1 3=dWhh1 4=eWhh0 5=dWhh0 6=Wcomb(dWih0@fcW)
// WX (eWih0 K=16 zero-pad-32 frags) @917504 (32KB)
// IMG_E (eWhh0 rows 0..383 swizzled) @950272 (96KB)
// IMG_D (dWhh0 rows 0..383 swizzled) @1048576 (96KB)
#define WS_WX  917504
#define WS_IME 950272
#define WS_IMD 1048576

__global__ void prep_kernel(
    const float* __restrict__ eWih0, const float* __restrict__ eWhh0,
    const float* __restrict__ eWih1, const float* __restrict__ eWhh1,
    const float* __restrict__ dWih0, const float* __restrict__ dWhh0,
    const float* __restrict__ dWih1, const float* __restrict__ dWhh1,
    const float* __restrict__ fcW, char* __restrict__ ws) {
  int idx = blockIdx.x * 256 + threadIdx.x;
  if (idx < 57344) {  // 7 mats x 8192 fragment records
    int m = idx >> 13, r = idx & 8191;
    int col = r >> 4, ks = (r >> 2) & 3, hi = r & 3;
    s16x8 v;
    if (m == 6) {  // Wcomb[col][k] = dWih0[col][0]*fcW[0][k]+dWih0[col][1]*fcW[1][k]
      float w0 = dWih0[col * 2 + 0], w1 = dWih0[col * 2 + 1];
#pragma unroll
      for (int j = 0; j < 8; ++j) {
        int k = ks * 32 + hi * 8 + j;
        v[j] = (short)f2h(w0 * fcW[k] + w1 * fcW[128 + k]);
      }
    } else {
      const float* W;
      switch (m) {
        case 0: W = eWih1; break;
        case 1: W = eWhh1; break;
        case 2: W = dWih1; break;
        case 3: W = dWhh1; break;
        case 4: W = eWhh0; break;
        default: W = dWhh0; break;
      }
      const float* p = W + col * 128 + ks * 32 + hi * 8;
#pragma unroll
      for (int j = 0; j < 8; ++j) v[j] = (short)f2h(p[j]);
    }
    *(s16x8*)(ws + m * 131072 + ks * 32768 + col * 64 + hi * 16) = v;
  } else if (idx < 59392) {  // WX frags
    int r3 = idx - 57344;
    int col = r3 >> 2, hi = r3 & 3;
    s16x8 v;
#pragma unroll
    for (int j = 0; j < 8; ++j) v[j] = 0;
    if (hi < 2) {
      const float* p = eWih0 + col * 16 + hi * 8;
#pragma unroll
      for (int j = 0; j < 8; ++j) v[j] = (short)f2h(p[j]);
    }
    *(s16x8*)(ws + WS_WX + col * 64 + hi * 16) = v;
  } else if (idx < 71680) {  // swizzled 3-gate images (rows 0..383)
    int r2 = idx - 59392;
    int m = (r2 >= 6144), rr = m ? r2 - 6144 : r2;
    int row = rr >> 4, s = rr & 15;
    const float* p = (m ? dWhh0 : eWhh0) + row * 128 + s * 8;
    s16x8 v;
#pragma unroll
    for (int j = 0; j < 8; ++j) v[j] = (short)f2h(p[j]);
    *(s16x8*)(ws + (m ? WS_IMD : WS_IME) + row * 256 + (((s ^ row) & 15) << 4)) = v;
  }
}

#define SMEM_BYTES 136960

__global__ __launch_bounds__(512, 2) void fused_kernel(
    const float* __restrict__ x,
    const float* __restrict__ ebih0, const float* __restrict__ ebhh0,
    const float* __restrict__ ebih1, const float* __restrict__ ebhh1,
    const float* __restrict__ dWih0,
    const float* __restrict__ dbih0, const float* __restrict__ dbhh0,
    const float* __restrict__ dbih1, const float* __restrict__ dbhh1,
    const float* __restrict__ fcW, const float* __restrict__ fcb,
    const char* __restrict__ ws, float* __restrict__ out) {
  extern __shared__ char smem[];
  char* wL   = smem;                       // 98304: 3-gate W_hh0 image
  char* h0B  = smem + 98304;               // 2 x 8192
  char* h1B  = smem + 114688;              // 2 x 8192
  char* xB   = smem + 131072;              // 2 x 2560
  float* inpL = (float*)(smem + 136192);   // 32x2 fp32 (decoder t=0 input)
  char* fcwL = smem + 136448;              // 2x128 fp16

  const int tid = threadIdx.x;
  const int w = tid >> 6, l = tid & 63, lo = l & 15, hi = l >> 4;
  const int row0 = blockIdx.x * 32;
  const int colb = w * 16;
  const int obase = (colb + lo) * 64 + hi * 16;   // frag offset, gate 0
  const int obase3 = obase + 384 * 64;            // gate 3

  // ================= init =================
  {  // stage IMG_E -> wL
    const int4* src = (const int4*)(ws + WS_IME);
    int4* dst = (int4*)wL;
    for (int i = tid; i < 6144; i += 512) dst[i] = src[i];
  }
  {  // zero h0B,h1B,xB (37888 B contiguous from h0B)
    int4 z = make_int4(0, 0, 0, 0);
    int4* p = (int4*)h0B;
    for (int i = tid; i < 2368; i += 512) p[i] = z;
  }

  float b0[4], b1[4];
  s16x8 wx0[4];
#pragma unroll
  for (int g = 0; g < 4; ++g) {
    int col = g * 128 + colb + lo;
    b0[g] = ebih0[col] + ebhh0[col];
    b1[g] = ebih1[col] + ebhh1[col];
    wx0[g] = *(const s16x8*)(ws + WS_WX + g * 8192 + obase);
  }
  float c0s[2][4], c1s[2][4];
#pragma unroll
  for (int rt = 0; rt < 2; ++rt)
#pragma unroll
    for (int r = 0; r < 4; ++r) { c0s[rt][r] = 0.f; c1s[rt][r] = 0.f; }

  const int xr = tid >> 4, xf = tid & 15;
  const float* xrow = x + (long long)(row0 + xr) * 1600 + xf;
  // stage x_0 into xB[0]
  *(unsigned short*)(xB + xr * 80 + xf * 2) = f2h(xrow[0]);
  float xv = xrow[16];  // x_1
  int cur = 0;
  __syncthreads();

  // ================= encoder: 101 fused phases, 1 barrier each ============
  for (int k = 0; k <= 100; ++k) {
    char* h0r = h0B + cur * 8192;
    char* h0w = h0B + (cur ^ 1) * 8192;
    char* h1r = h1B + cur * 8192;
    char* h1w = h1B + (cur ^ 1) * 8192;
    char* xc  = xB + cur * 2560;
    char* xn  = xB + (cur ^ 1) * 2560;

    float xv_stage = xv;                       // x_{k+1}
    if (k < 98) xv = xrow[(k + 2) * 16];       // issue prefetch early

    if (k > 0) {  // ---- layer 1: h1(k) = cell1(h0(k), h1(k-1))
      f32x4 acc[2][4];
#pragma unroll
      for (int g = 0; g < 4; ++g) { acc[0][g] = splat4(b1[g]); acc[1][g] = splat4(b1[g]); }
      int lf = 0;
      asm("" : "+s"(lf));  // defeat LICM
      const char* W1 = ws + lf;  // mats 0/1
#pragma unroll
      for (int s = 0; s < 8; ++s) {
        const char* src = (s < 4) ? h0r : h1r;
        int ks = s & 3;
        const char* wk = W1 + (s < 4 ? 0 : 131072) + ks * 32768 + obase;
        s16x8 a0 = ldA(src, 0, ks, lo, hi), a1 = ldA(src, 1, ks, lo, hi);
#pragma unroll
        for (int g = 0; g < 4; ++g) {
          s16x8 bb = *(const s16x8*)(wk + g * 8192);
          acc[0][g] = mf(a0, bb, acc[0][g]);
          acc[1][g] = mf(a1, bb, acc[1][g]);
        }
      }
#pragma unroll
      for (int rt = 0; rt < 2; ++rt)
#pragma unroll
        for (int r = 0; r < 4; ++r)
          storeH(h1w, rt * 16 + hi * 4 + r, colb + lo,
                 cellup(acc[rt][0][r], acc[rt][1][r], acc[rt][2][r], acc[rt][3][r], c1s[rt][r]));
    }

    __builtin_amdgcn_sched_barrier(0x30);  // only VMEM may cross (prefetch)

    if (k < 100) {  // ---- layer 0: h0(k+1) = cell0(x_k, h0(k))
      f32x4 acc[2][4];
#pragma unroll
      for (int g = 0; g < 4; ++g) { acc[0][g] = splat4(b0[g]); acc[1][g] = splat4(b0[g]); }
      {
        s16x8 a0 = *(const s16x8*)(xc + lo * 80 + hi * 16);
        s16x8 a1 = *(const s16x8*)(xc + (16 + lo) * 80 + hi * 16);
#pragma unroll
        for (int g = 0; g < 4; ++g) {
          acc[0][g] = mf(a0, wx0[g], acc[0][g]);
          acc[1][g] = mf(a1, wx0[g], acc[1][g]);
        }
      }
      int lf = 0;
      asm("" : "+s"(lf));
      const char* W0 = ws + 4 * 131072 + lf;  // eWhh0 records (gate 3)
#pragma unroll
      for (int ks = 0; ks < 4; ++ks) {
        s16x8 a0 = ldA(h0r, 0, ks, lo, hi), a1 = ldA(h0r, 1, ks, lo, hi);
#pragma unroll
        for (int g = 0; g < 3; ++g) {
          s16x8 bb = ldB(wL, g * 128 + colb, ks, lo, hi);
          acc[0][g] = mf(a0, bb, acc[0][g]);
          acc[1][g] = mf(a1, bb, acc[1][g]);
        }
        s16x8 b3 = *(const s16x8*)(W0 + ks * 32768 + obase3);
        acc[0][3] = mf(a0, b3, acc[0][3]);
        acc[1][3] = mf(a1, b3, acc[1][3]);
      }
#pragma unroll
      for (int rt = 0; rt < 2; ++rt)
#pragma unroll
        for (int r = 0; r < 4; ++r)
          storeH(h0w, rt * 16 + hi * 4 + r, colb + lo,
                 cellup(acc[rt][0][r], acc[rt][1][r], acc[rt][2][r], acc[rt][3][r], c0s[rt][r]));
      if (k < 99)  // stage x_{k+1} for next phase
        *(unsigned short*)(xn + xr * 80 + xf * 2) = f2h(xv_stage);
    }
    __syncthreads();
    cur ^= 1;
  }
  // final states: h0(100) in h0B[cur^1], h1(100) in h1B[cur]
  int dc0 = cur ^ 1, dc1 = cur;

  // ================= restage for decoder =================
  {  // IMG_D -> wL (safe: k=100 phase used no wL)
    const int4* src = (const int4*)(ws + WS_IMD);
    int4* dst = (int4*)wL;
    for (int i = tid; i < 6144; i += 512) dst[i] = src[i];
  }
  if (tid < 64) {  // dec_in = x[:, 99, :2]
    int r = tid >> 1, o = tid & 1;
    inpL[r * 2 + o] = x[(long long)(row0 + r) * 1600 + 1584 + o];
  }
  if (tid < 256) {
    int o = tid >> 7, k2 = tid & 127;
    *(unsigned short*)(fcwL + o * 256 + k2 * 2) = f2h(fcW[o * 128 + k2]);
  }
  float dwx[4][2], b0f[4];
#pragma unroll
  for (int g = 0; g < 4; ++g) {
    int col = g * 128 + colb + lo;
    b0[g] = dbih0[col] + dbhh0[col];
    b1[g] = dbih1[col] + dbhh1[col];
    dwx[g][0] = dWih0[col * 2 + 0];
    dwx[g][1] = dWih0[col * 2 + 1];
  }
  float fb0 = fcb[0], fb1 = fcb[1];
#pragma unroll
  for (int g = 0; g < 4; ++g) b0f[g] = b0[g] + dwx[g][0] * fb0 + dwx[g][1] * fb1;
  __syncthreads();

  // ================= decoder =================
  // Phase A0 (t=0): h0^1 = cell0(inp0 [VALU], h0^0 @ dWhh0)
  {
    f32x4 acc[2][4];
    char* h0r = h0B + dc0 * 8192;
    char* h0w = h0B + (dc0 ^ 1) * 8192;
#pragma unroll
    for (int rt = 0; rt < 2; ++rt)
#pragma unroll
      for (int r = 0; r < 4; ++r) {
        float2 ip = *(const float2*)(inpL + (rt * 16 + hi * 4 + r) * 2);
#pragma unroll
        for (int g = 0; g < 4; ++g)
          acc[rt][g][r] = b0[g] + ip.x * dwx[g][0] + ip.y * dwx[g][1];
      }
    int lf = 0;
    asm("" : "+s"(lf));
    const char* WA = ws + 5 * 131072 + lf;  // dWhh0 records (gate 3)
#pragma unroll
    for (int ks = 0; ks < 4; ++ks) {
      s16x8 a0 = ldA(h0r, 0, ks, lo, hi), a1 = ldA(h0r, 1, ks, lo, hi);
#pragma unroll
      for (int g = 0; g < 3; ++g) {
        s16x8 bb = ldB(wL, g * 128 + colb, ks, lo, hi);
        acc[0][g] = mf(a0, bb, acc[0][g]);
        acc[1][g] = mf(a1, bb, acc[1][g]);
      }
      s16x8 b3 = *(const s16x8*)(WA + ks * 32768 + obase3);
      acc[0][3] = mf(a0, b3, acc[0][3]);
      acc[1][3] = mf(a1, b3, acc[1][3]);
    }
#pragma unroll
    for (int rt = 0; rt < 2; ++rt)
#pragma unroll
      for (int r = 0; r < 4; ++r)
        storeH(h0w, rt * 16 + hi * 4 + r, colb + lo,
               cellup(acc[rt][0][r], acc[rt][1][r], acc[rt][2][r], acc[rt][3][r], c0s[rt][r]));
    dc0 ^= 1;
    __syncthreads();
  }

  for (int t = 0; t < 60; ++t) {
    // ---- Phase B(t): h1^{t+1} = cell1(h0^{t+1} @ dWih1 + h1^t @ dWhh1)
    {
      char* h0r = h0B + dc0 * 8192;
      char* h1r = h1B + dc1 * 8192;
      char* h1w = h1B + (dc1 ^ 1) * 8192;
      f32x4 acc[2][4];
#pragma unroll
      for (int g = 0; g < 4; ++g) { acc[0][g] = splat4(b1[g]); acc[1][g] = splat4(b1[g]); }
      int lf = 0;
      asm("" : "+s"(lf));
      const char* WB = ws + 2 * 131072 + lf;  // mats 2/3
#pragma unroll
      for (int s = 0; s < 8; ++s) {
        const char* src = (s < 4) ? h0r : h1r;
        int ks = s & 3;
        const char* wk = WB + (s < 4 ? 0 : 131072) + ks * 32768 + obase;
        s16x8 a0 = ldA(src, 0, ks, lo, hi), a1 = ldA(src, 1, ks, lo, hi);
#pragma unroll
        for (int g = 0; g < 4; ++g) {
          s16x8 bb = *(const s16x8*)(wk + g * 8192);
          acc[0][g] = mf(a0, bb, acc[0][g]);
          acc[1][g] = mf(a1, bb, acc[1][g]);
        }
      }
#pragma unroll
      for (int rt = 0; rt < 2; ++rt)
#pragma unroll
        for (int r = 0; r < 4; ++r)
          storeH(h1w, rt * 16 + hi * 4 + r, colb + lo,
                 cellup(acc[rt][0][r], acc[rt][1][r], acc[rt][2][r], acc[rt][3][r], c1s[rt][r]));
      dc1 ^= 1;
      __syncthreads();
    }

    // ---- Phase A(t+1): h0^{t+2} = cell0'(h1^{t+1} @ Wcomb + h0^{t+1} @ dWhh0)
    //      + FC output out(t) = FC(h1^{t+1})  (waves 0,1)
    {
      char* h1r = h1B + dc1 * 8192;   // h1^{t+1}
      if (w < 2) {
        int row = w * 16 + lo;
        int o = hi & 1, kh = hi >> 1;
        float sum = 0.f;
#pragma unroll
        for (int cc = 0; cc < 8; ++cc) {
          s16x8 hv = *(const s16x8*)(h1r + swz(row, kh * 8 + cc));
          s16x8 wv = *(const s16x8*)(fcwL + o * 256 + (kh * 8 + cc) * 16);
#pragma unroll
          for (int j = 0; j < 8; ++j) sum += h2f(hv[j]) * h2f(wv[j]);
        }
        sum += __shfl_xor(sum, 32, 64);
        if (l < 32)
          out[((long long)(row0 + row) * 60 + t) * 2 + o] = sum + (o ? fb1 : fb0);
      }
      if (t < 59) {
        char* h0r = h0B + dc0 * 8192;
        char* h0w = h0B + (dc0 ^ 1) * 8192;
        f32x4 acc[2][4];
#pragma unroll
        for (int g = 0; g < 4; ++g) { acc[0][g] = splat4(b0f[g]); acc[1][g] = splat4(b0f[g]); }
        int lf = 0;
        asm("" : "+s"(lf));
        const char* WA = ws + 5 * 131072 + lf;   // dWhh0 gate-3 records
        const char* WC = ws + 6 * 131072 + lf;   // Wcomb records
#pragma unroll
        for (int ks = 0; ks < 4; ++ks) {
          s16x8 a0 = ldA(h0r, 0, ks, lo, hi), a1 = ldA(h0r, 1, ks, lo, hi);
          s16x8 e0 = ldA(h1r, 0, ks, lo, hi), e1 = ldA(h1r, 1, ks, lo, hi);
#pragma unroll
          for (int g = 0; g < 3; ++g) {
            s16x8 bb = ldB(wL, g * 128 + colb, ks, lo, hi);
            acc[0][g] = mf(a0, bb, acc[0][g]);
            acc[1][g] = mf(a1, bb, acc[1][g]);
          }
          s16x8 b3 = *(const s16x8*)(WA + ks * 32768 + obase3);
          acc[0][3] = mf(a0, b3, acc[0][3]);
          acc[1][3] = mf(a1, b3, acc[1][3]);
#pragma unroll
          for (int g = 0; g < 4; ++g) {
            s16x8 bc = *(const s16x8*)(WC + ks * 32768 + g * 8192 + obase);
            acc[0][g] = mf(e0, bc, acc[0][g]);
            acc[1][g] = mf(e1, bc, acc[1][g]);
          }
        }
#pragma unroll
        for (int rt = 0; rt < 2; ++rt)
#pragma unroll
          for (int r = 0; r < 4; ++r)
            storeH(h0w, rt * 16 + hi * 4 + r, colb + lo,
                   cellup(acc[rt][0][r], acc[rt][1][r], acc[rt][2][r], acc[rt][3][r], c0s[rt][r]));
        dc0 ^= 1;
      }
      __syncthreads();
    }
  }
}

extern "C" void kernel_launch(void* const* d_in, const int* in_sizes, int n_in,
                              void* d_out, int out_size, void* d_ws, size_t ws_size,
                              hipStream_t stream) {
  (void)in_sizes; (void)n_in; (void)out_size; (void)ws_size;
  const float* x      = (const float*)d_in[0];
  // d_in[1] = target_len (60), hardcoded
  const float* eWih0  = (const float*)d_in[2];
  const float* eWhh0  = (const float*)d_in[3];
  const float* ebih0  = (const float*)d_in[4];
  const float* ebhh0  = (const float*)d_in[5];
  const float* eWih1  = (const float*)d_in[6];
  const float* eWhh1  = (const float*)d_in[7];
  const float* ebih1  = (const float*)d_in[8];
  const float* ebhh1  = (const float*)d_in[9];
  const float* dWih0  = (const float*)d_in[10];
  const float* dWhh0  = (const float*)d_in[11];
  const float* dbih0  = (const float*)d_in[12];
  const float* dbhh0  = (const float*)d_in[13];
  const float* dWih1  = (const float*)d_in[14];
  const float* dWhh1  = (const float*)d_in[15];
  const float* dbih1  = (const float*)d_in[16];
  const float* dbhh1  = (const float*)d_in[17];
  const float* fcW    = (const float*)d_in[18];
  const float* fcb    = (const float*)d_in[19];
  float* out          = (float*)d_out;
  char* ws            = (char*)d_ws;

  prep_kernel<<<280, 256, 0, stream>>>(eWih0, eWhh0, eWih1, eWhh1,
                                       dWih0, dWhh0, dWih1, dWhh1, fcW, ws);

  hipFuncSetAttribute(reinterpret_cast<const void*>(fused_kernel),
                      hipFuncAttributeMaxDynamicSharedMemorySize, SMEM_BYTES);

  fused_kernel<<<256, 512, SMEM_BYTES, stream>>>(
      x, ebih0, ebhh0, ebih1, ebhh1, dWih0, dbih0, dbhh0, dbih1, dbhh1,
      fcW, fcb, ws, out);
}

// Round 17
// 1152.831 us; speedup vs baseline: 1.5465x; 1.0270x over previous
//
#include <hip/hip_runtime.h>

// R15: R14 with the distributed-FC bug fixed (R14's seg=l&7 covered only
// cols 0..63 -> absmax 2.6e-2; now each lane covers slots seg and seg+8 ->
// full 128-col dot). All R14 perf machinery retained:
//  - static __shared__ (compiler sees 1 block/CU -> full VGPR budget)
//  - double-buffered B-frag pipelining (enc L1, dec B, dec A Wcomb)
//  - preloaded gate-3 frags; FC distributed across all 8 waves
//  - tanh = 1 - 2*rcp(exp(2x)+1); rcp-based sigmoid
//  - fused encoder phase (1 barrier/step), decoder FC-fold (2 barriers/step)

using s16x8 = __attribute__((ext_vector_type(8))) short;
using h16x8 = __attribute__((ext_vector_type(8))) _Float16;
using f32x4 = __attribute__((ext_vector_type(4))) float;

#define DEV static __device__ __forceinline__

DEV unsigned short f2h(float f) {
  _Float16 h = (_Float16)f;  // RNE
  return __builtin_bit_cast(unsigned short, h);
}
DEV float h2f(short h) {
  return (float)__builtin_bit_cast(_Float16, (unsigned short)h);
}
DEV float rcp_(float x) { return __builtin_amdgcn_rcpf(x); }
DEV float sigm(float v) { return rcp_(1.0f + __expf(-v)); }
DEV float tanh_(float v) {  // 1 - 2/(e^{2v}+1); exact at +-inf, ~1e-7 abs
  float e = __expf(2.0f * v);
  return 1.0f - 2.0f * rcp_(e + 1.0f);
}
DEV f32x4 mf(s16x8 a, s16x8 b, f32x4 c) {
  return __builtin_amdgcn_mfma_f32_16x16x32_f16(
      __builtin_bit_cast(h16x8, a), __builtin_bit_cast(h16x8, b), c, 0, 0, 0);
}
DEV f32x4 splat4(float v) { f32x4 r = {v, v, v, v}; return r; }

// [rows][128] fp16 buffer; 16 slots of 8 fp16 per row, XOR-swizzled.
DEV int swz(int row, int slot) { return row * 256 + (((slot ^ row) & 15) << 4); }
DEV s16x8 ldA(const char* buf, int rt, int ks, int lo, int hi) {
  return *(const s16x8*)(buf + swz(rt * 16 + lo, ks * 4 + hi));
}
DEV s16x8 ldB(const char* wlds, int colbase, int ks, int lo, int hi) {
  return *(const s16x8*)(wlds + swz(colbase + lo, ks * 4 + hi));
}
DEV void storeH(char* buf, int row, int col, unsigned short v) {
  int addr = row * 256 + ((((col >> 3) ^ row) & 15) << 4) + (col & 7) * 2;
  *(unsigned short*)(buf + addr) = v;
}
DEV unsigned short cellup(float gi, float gf, float gg, float go, float& c) {
  float i = sigm(gi), f = sigm(gf), g2 = tanh_(gg), o = sigm(go);
  c = f * c + i * g2;
  return f2h(o * tanh_(c));
}

// ---- d_ws layout (bytes) ----
// frag records, mats m*131072, addr = m*131072 + ks*32768 + col*64 + hi*16
//   m: 0=eWih1 1=eWhh1 2=dWih1 3=dWhh1 4=eWhh0 5=dWhh0 6=Wcomb(dWih0@fcW)
// WX (eWih0 K=16 zero-pad-32 frags) @917504 (32KB)
// IMG_E (eWhh0 rows 0..383 swizzled) @950272 (96KB)
// IMG_D (dWhh0 rows 0..383 swizzled) @1048576 (96KB)
#define WS_WX  917504
#define WS_IME 950272
#define WS_IMD 1048576

__global__ void prep_kernel(
    const float* __restrict__ eWih0, const float* __restrict__ eWhh0,
    const float* __restrict__ eWih1, const float* __restrict__ eWhh1,
    const float* __restrict__ dWih0, const float* __restrict__ dWhh0,
    const float* __restrict__ dWih1, const float* __restrict__ dWhh1,
    const float* __restrict__ fcW, char* __restrict__ ws) {
  int idx = blockIdx.x * 256 + threadIdx.x;
  if (idx < 57344) {  // 7 mats x 8192 fragment records
    int m = idx >> 13, r = idx & 8191;
    int col = r >> 4, ks = (r >> 2) & 3, hi = r & 3;
    s16x8 v;
    if (m == 6) {  // Wcomb[col][k] = dWih0[col][0]*fcW[0][k]+dWih0[col][1]*fcW[1][k]
      float w0 = dWih0[col * 2 + 0], w1 = dWih0[col * 2 + 1];
#pragma unroll
      for (int j = 0; j < 8; ++j) {
        int k = ks * 32 + hi * 8 + j;
        v[j] = (short)f2h(w0 * fcW[k] + w1 * fcW[128 + k]);
      }
    } else {
      const float* W;
      switch (m) {
        case 0: W = eWih1; break;
        case 1: W = eWhh1; break;
        case 2: W = dWih1; break;
        case 3: W = dWhh1; break;
        case 4: W = eWhh0; break;
        default: W = dWhh0; break;
      }
      const float* p = W + col * 128 + ks * 32 + hi * 8;
#pragma unroll
      for (int j = 0; j < 8; ++j) v[j] = (short)f2h(p[j]);
    }
    *(s16x8*)(ws + m * 131072 + ks * 32768 + col * 64 + hi * 16) = v;
  } else if (idx < 59392) {  // WX frags
    int r3 = idx - 57344;
    int col = r3 >> 2, hi = r3 & 3;
    s16x8 v;
#pragma unroll
    for (int j = 0; j < 8; ++j) v[j] = 0;
    if (hi < 2) {
      const float* p = eWih0 + col * 16 + hi * 8;
#pragma unroll
      for (int j = 0; j < 8; ++j) v[j] = (short)f2h(p[j]);
    }
    *(s16x8*)(ws + WS_WX + col * 64 + hi * 16) = v;
  } else if (idx < 71680) {  // swizzled 3-gate images (rows 0..383)
    int r2 = idx - 59392;
    int m = (r2 >= 6144), rr = m ? r2 - 6144 : r2;
    int row = rr >> 4, s = rr & 15;
    const float* p = (m ? dWhh0 : eWhh0) + row * 128 + s * 8;
    s16x8 v;
#pragma unroll
    for (int j = 0; j < 8; ++j) v[j] = (short)f2h(p[j]);
    *(s16x8*)(ws + (m ? WS_IMD : WS_IME) + row * 256 + (((s ^ row) & 15) << 4)) = v;
  }
}

__global__ __launch_bounds__(512, 2) void fused_kernel(
    const float* __restrict__ x,
    const float* __restrict__ ebih0, const float* __restrict__ ebhh0,
    const float* __restrict__ ebih1, const float* __restrict__ ebhh1,
    const float* __restrict__ dWih0,
    const float* __restrict__ dbih0, const float* __restrict__ dbhh0,
    const float* __restrict__ dbih1, const float* __restrict__ dbhh1,
    const float* __restrict__ fcW, const float* __restrict__ fcb,
    const char* __restrict__ ws, float* __restrict__ out) {
  // STATIC shared: compiler sees 136960B -> knows 1 block/CU -> full VGPR budget
  __shared__ __align__(16) char smem[136960];
  char* wL   = smem;                       // 98304: 3-gate W_hh0 image
  char* h0B  = smem + 98304;               // 2 x 8192
  char* h1B  = smem + 114688;              // 2 x 8192
  char* xB   = smem + 131072;              // 2 x 2560
  float* inpL = (float*)(smem + 136192);   // 32x2 fp32 (decoder t=0 input)
  char* fcwL = smem + 136448;              // 2x128 fp16

  const int tid = threadIdx.x;
  const int w = tid >> 6, l = tid & 63, lo = l & 15, hi = l >> 4;
  const int row0 = blockIdx.x * 32;
  const int colb = w * 16;
  const int obase = (colb + lo) * 64 + hi * 16;   // frag offset, gate 0
  const int obase3 = obase + 384 * 64;            // gate 3

  // ================= init =================
  {  // stage IMG_E -> wL
    const int4* src = (const int4*)(ws + WS_IME);
    int4* dst = (int4*)wL;
    for (int i = tid; i < 6144; i += 512) dst[i] = src[i];
  }
  {  // zero h0B,h1B,xB (37888 B contiguous from h0B)
    int4 z = make_int4(0, 0, 0, 0);
    int4* p = (int4*)h0B;
    for (int i = tid; i < 2368; i += 512) p[i] = z;
  }

  float b0[4], b1[4];
  s16x8 wx0[4];
#pragma unroll
  for (int g = 0; g < 4; ++g) {
    int col = g * 128 + colb + lo;
    b0[g] = ebih0[col] + ebhh0[col];
    b1[g] = ebih1[col] + ebhh1[col];
    wx0[g] = *(const s16x8*)(ws + WS_WX + g * 8192 + obase);
  }
  float c0s[2][4], c1s[2][4];
#pragma unroll
  for (int rt = 0; rt < 2; ++rt)
#pragma unroll
    for (int r = 0; r < 4; ++r) { c0s[rt][r] = 0.f; c1s[rt][r] = 0.f; }

  const int xr = tid >> 4, xf = tid & 15;
  const float* xrow = x + (long long)(row0 + xr) * 1600 + xf;
  *(unsigned short*)(xB + xr * 80 + xf * 2) = f2h(xrow[0]);  // x_0
  float xv = xrow[16];  // x_1
  int cur = 0;
  __syncthreads();

  // ================= encoder: 101 fused phases, 1 barrier each ============
  for (int k = 0; k <= 100; ++k) {
    char* h0r = h0B + cur * 8192;
    char* h0w = h0B + (cur ^ 1) * 8192;
    char* h1r = h1B + cur * 8192;
    char* h1w = h1B + (cur ^ 1) * 8192;
    char* xc  = xB + cur * 2560;
    char* xn  = xB + (cur ^ 1) * 2560;

    float xv_stage = xv;                       // x_{k+1}
    if (k < 98) xv = xrow[(k + 2) * 16];       // issue prefetch early

    if (k > 0) {  // ---- layer 1: h1(k) = cell1(h0(k), h1(k-1))
      f32x4 acc[2][4];
#pragma unroll
      for (int g = 0; g < 4; ++g) { acc[0][g] = splat4(b1[g]); acc[1][g] = splat4(b1[g]); }
      int lf = 0;
      asm("" : "+s"(lf));  // defeat LICM
      const char* W1 = ws + lf;  // mats 0/1
      s16x8 bf0[4], bf1[4];
#pragma unroll
      for (int g = 0; g < 4; ++g)
        bf0[g] = *(const s16x8*)(W1 + g * 8192 + obase);  // s=0 group
#pragma unroll
      for (int s = 0; s < 8; ++s) {
        s16x8* bcur = (s & 1) ? bf1 : bf0;
        s16x8* bnxt = (s & 1) ? bf0 : bf1;
        if (s < 7) {
          const char* wkn = W1 + ((s + 1) < 4 ? 0 : 131072) + ((s + 1) & 3) * 32768 + obase;
#pragma unroll
          for (int g = 0; g < 4; ++g) bnxt[g] = *(const s16x8*)(wkn + g * 8192);
        }
        const char* src = (s < 4) ? h0r : h1r;
        int ks = s & 3;
        s16x8 a0 = ldA(src, 0, ks, lo, hi), a1 = ldA(src, 1, ks, lo, hi);
#pragma unroll
        for (int g = 0; g < 4; ++g) {
          acc[0][g] = mf(a0, bcur[g], acc[0][g]);
          acc[1][g] = mf(a1, bcur[g], acc[1][g]);
        }
      }
#pragma unroll
      for (int rt = 0; rt < 2; ++rt)
#pragma unroll
        for (int r = 0; r < 4; ++r)
          storeH(h1w, rt * 16 + hi * 4 + r, colb + lo,
                 cellup(acc[rt][0][r], acc[rt][1][r], acc[rt][2][r], acc[rt][3][r], c1s[rt][r]));
    }

    if (k < 100) {  // ---- layer 0: h0(k+1) = cell0(x_k, h0(k))
      f32x4 acc[2][4];
#pragma unroll
      for (int g = 0; g < 4; ++g) { acc[0][g] = splat4(b0[g]); acc[1][g] = splat4(b0[g]); }
      int lf = 0;
      asm("" : "+s"(lf));
      const char* W0 = ws + 4 * 131072 + lf;  // eWhh0 records (gate 3)
      s16x8 b3[4];
#pragma unroll
      for (int ks = 0; ks < 4; ++ks)
        b3[ks] = *(const s16x8*)(W0 + ks * 32768 + obase3);
      {
        s16x8 a0 = *(const s16x8*)(xc + lo * 80 + hi * 16);
        s16x8 a1 = *(const s16x8*)(xc + (16 + lo) * 80 + hi * 16);
#pragma unroll
        for (int g = 0; g < 4; ++g) {
          acc[0][g] = mf(a0, wx0[g], acc[0][g]);
          acc[1][g] = mf(a1, wx0[g], acc[1][g]);
        }
      }
#pragma unroll
      for (int ks = 0; ks < 4; ++ks) {
        s16x8 a0 = ldA(h0r, 0, ks, lo, hi), a1 = ldA(h0r, 1, ks, lo, hi);
#pragma unroll
        for (int g = 0; g < 3; ++g) {
          s16x8 bb = ldB(wL, g * 128 + colb, ks, lo, hi);
          acc[0][g] = mf(a0, bb, acc[0][g]);
          acc[1][g] = mf(a1, bb, acc[1][g]);
        }
        acc[0][3] = mf(a0, b3[ks], acc[0][3]);
        acc[1][3] = mf(a1, b3[ks], acc[1][3]);
      }
#pragma unroll
      for (int rt = 0; rt < 2; ++rt)
#pragma unroll
        for (int r = 0; r < 4; ++r)
          storeH(h0w, rt * 16 + hi * 4 + r, colb + lo,
                 cellup(acc[rt][0][r], acc[rt][1][r], acc[rt][2][r], acc[rt][3][r], c0s[rt][r]));
      if (k < 99)  // stage x_{k+1} for next phase
        *(unsigned short*)(xn + xr * 80 + xf * 2) = f2h(xv_stage);
    }
    __syncthreads();
    cur ^= 1;
  }
  // final states: h0(100) in h0B[cur^1], h1(100) in h1B[cur]
  int dc0 = cur ^ 1, dc1 = cur;

  // ================= restage for decoder =================
  {  // IMG_D -> wL (safe: k=100 phase used no wL)
    const int4* src = (const int4*)(ws + WS_IMD);
    int4* dst = (int4*)wL;
    for (int i = tid; i < 6144; i += 512) dst[i] = src[i];
  }
  if (tid < 64) {  // dec_in = x[:, 99, :2]
    int r = tid >> 1, o = tid & 1;
    inpL[r * 2 + o] = x[(long long)(row0 + r) * 1600 + 1584 + o];
  }
  if (tid < 256) {
    int o = tid >> 7, k2 = tid & 127;
    *(unsigned short*)(fcwL + o * 256 + k2 * 2) = f2h(fcW[o * 128 + k2]);
  }
  float dwx[4][2], b0f[4];
#pragma unroll
  for (int g = 0; g < 4; ++g) {
    int col = g * 128 + colb + lo;
    b0[g] = dbih0[col] + dbhh0[col];
    b1[g] = dbih1[col] + dbhh1[col];
    dwx[g][0] = dWih0[col * 2 + 0];
    dwx[g][1] = dWih0[col * 2 + 1];
  }
  float fb0 = fcb[0], fb1 = fcb[1];
#pragma unroll
  for (int g = 0; g < 4; ++g) b0f[g] = b0[g] + dwx[g][0] * fb0 + dwx[g][1] * fb1;
  __syncthreads();

  // ================= decoder =================
  // Phase A0 (t=0): h0^1 = cell0(inp0 [VALU], h0^0 @ dWhh0)
  {
    f32x4 acc[2][4];
    char* h0r = h0B + dc0 * 8192;
    char* h0w = h0B + (dc0 ^ 1) * 8192;
#pragma unroll
    for (int rt = 0; rt < 2; ++rt)
#pragma unroll
      for (int r = 0; r < 4; ++r) {
        float2 ip = *(const float2*)(inpL + (rt * 16 + hi * 4 + r) * 2);
#pragma unroll
        for (int g = 0; g < 4; ++g)
          acc[rt][g][r] = b0[g] + ip.x * dwx[g][0] + ip.y * dwx[g][1];
      }
    int lf = 0;
    asm("" : "+s"(lf));
    const char* WA = ws + 5 * 131072 + lf;  // dWhh0 records (gate 3)
    s16x8 b3[4];
#pragma unroll
    for (int ks = 0; ks < 4; ++ks)
      b3[ks] = *(const s16x8*)(WA + ks * 32768 + obase3);
#pragma unroll
    for (int ks = 0; ks < 4; ++ks) {
      s16x8 a0 = ldA(h0r, 0, ks, lo, hi), a1 = ldA(h0r, 1, ks, lo, hi);
#pragma unroll
      for (int g = 0; g < 3; ++g) {
        s16x8 bb = ldB(wL, g * 128 + colb, ks, lo, hi);
        acc[0][g] = mf(a0, bb, acc[0][g]);
        acc[1][g] = mf(a1, bb, acc[1][g]);
      }
      acc[0][3] = mf(a0, b3[ks], acc[0][3]);
      acc[1][3] = mf(a1, b3[ks], acc[1][3]);
    }
#pragma unroll
    for (int rt = 0; rt < 2; ++rt)
#pragma unroll
      for (int r = 0; r < 4; ++r)
        storeH(h0w, rt * 16 + hi * 4 + r, colb + lo,
               cellup(acc[rt][0][r], acc[rt][1][r], acc[rt][2][r], acc[rt][3][r], c0s[rt][r]));
    dc0 ^= 1;
    __syncthreads();
  }

  for (int t = 0; t < 60; ++t) {
    // ---- Phase B(t): h1^{t+1} = cell1(h0^{t+1} @ dWih1 + h1^t @ dWhh1)
    {
      char* h0r = h0B + dc0 * 8192;
      char* h1r = h1B + dc1 * 8192;
      char* h1w = h1B + (dc1 ^ 1) * 8192;
      f32x4 acc[2][4];
#pragma unroll
      for (int g = 0; g < 4; ++g) { acc[0][g] = splat4(b1[g]); acc[1][g] = splat4(b1[g]); }
      int lf = 0;
      asm("" : "+s"(lf));
      const char* WB = ws + 2 * 131072 + lf;  // mats 2/3
      s16x8 bf0[4], bf1[4];
#pragma unroll
      for (int g = 0; g < 4; ++g)
        bf0[g] = *(const s16x8*)(WB + g * 8192 + obase);
#pragma unroll
      for (int s = 0; s < 8; ++s) {
        s16x8* bcur = (s & 1) ? bf1 : bf0;
        s16x8* bnxt = (s & 1) ? bf0 : bf1;
        if (s < 7) {
          const char* wkn = WB + ((s + 1) < 4 ? 0 : 131072) + ((s + 1) & 3) * 32768 + obase;
#pragma unroll
          for (int g = 0; g < 4; ++g) bnxt[g] = *(const s16x8*)(wkn + g * 8192);
        }
        const char* src = (s < 4) ? h0r : h1r;
        int ks = s & 3;
        s16x8 a0 = ldA(src, 0, ks, lo, hi), a1 = ldA(src, 1, ks, lo, hi);
#pragma unroll
        for (int g = 0; g < 4; ++g) {
          acc[0][g] = mf(a0, bcur[g], acc[0][g]);
          acc[1][g] = mf(a1, bcur[g], acc[1][g]);
        }
      }
#pragma unroll
      for (int rt = 0; rt < 2; ++rt)
#pragma unroll
        for (int r = 0; r < 4; ++r)
          storeH(h1w, rt * 16 + hi * 4 + r, colb + lo,
                 cellup(acc[rt][0][r], acc[rt][1][r], acc[rt][2][r], acc[rt][3][r], c1s[rt][r]));
      dc1 ^= 1;
      __syncthreads();
    }

    // ---- Phase A(t+1): FC out(t) distributed over all waves, then
    //      h0^{t+2} = cell0'(h1^{t+1} @ Wcomb + h0^{t+1} @ dWhh0)
    {
      char* h1r = h1B + dc1 * 8192;   // h1^{t+1}
      {  // distributed FC: 64 sums (32 rows x 2 outs), 8 lanes x 2 slots each
        int rl = l >> 4, oo = (l >> 3) & 1, seg = l & 7;
        int row = w * 4 + rl;
        s16x8 hv0 = *(const s16x8*)(h1r + swz(row, seg));
        s16x8 wv0 = *(const s16x8*)(fcwL + oo * 256 + seg * 16);
        s16x8 hv1 = *(const s16x8*)(h1r + swz(row, seg + 8));
        s16x8 wv1 = *(const s16x8*)(fcwL + oo * 256 + (seg + 8) * 16);
        float sum = 0.f;
#pragma unroll
        for (int j = 0; j < 8; ++j)
          sum += h2f(hv0[j]) * h2f(wv0[j]) + h2f(hv1[j]) * h2f(wv1[j]);
        sum += __shfl_xor(sum, 1);
        sum += __shfl_xor(sum, 2);
        sum += __shfl_xor(sum, 4);
        if (seg == 0)
          out[((long long)(row0 + row) * 60 + t) * 2 + oo] = sum + (oo ? fb1 : fb0);
      }
      if (t < 59) {
        char* h0r = h0B + dc0 * 8192;
        char* h0w = h0B + (dc0 ^ 1) * 8192;
        f32x4 acc[2][4];
#pragma unroll
        for (int g = 0; g < 4; ++g) { acc[0][g] = splat4(b0f[g]); acc[1][g] = splat4(b0f[g]); }
        int lf = 0;
        asm("" : "+s"(lf));
        const char* WA = ws + 5 * 131072 + lf;   // dWhh0 gate-3 records
        const char* WC = ws + 6 * 131072 + lf;   // Wcomb records
        s16x8 b3[4];
#pragma unroll
        for (int ks = 0; ks < 4; ++ks)
          b3[ks] = *(const s16x8*)(WA + ks * 32768 + obase3);
        s16x8 cf0[4], cf1[4];
#pragma unroll
        for (int g = 0; g < 4; ++g)
          cf0[g] = *(const s16x8*)(WC + g * 8192 + obase);
#pragma unroll
        for (int ks = 0; ks < 4; ++ks) {
          s16x8* ccur = (ks & 1) ? cf1 : cf0;
          s16x8* cnxt = (ks & 1) ? cf0 : cf1;
          if (ks < 3) {
            const char* wkn = WC + (ks + 1) * 32768 + obase;
#pragma unroll
            for (int g = 0; g < 4; ++g) cnxt[g] = *(const s16x8*)(wkn + g * 8192);
          }
          s16x8 a0 = ldA(h0r, 0, ks, lo, hi), a1 = ldA(h0r, 1, ks, lo, hi);
          s16x8 e0 = ldA(h1r, 0, ks, lo, hi), e1 = ldA(h1r, 1, ks, lo, hi);
#pragma unroll
          for (int g = 0; g < 3; ++g) {
            s16x8 bb = ldB(wL, g * 128 + colb, ks, lo, hi);
            acc[0][g] = mf(a0, bb, acc[0][g]);
            acc[1][g] = mf(a1, bb, acc[1][g]);
          }
          acc[0][3] = mf(a0, b3[ks], acc[0][3]);
          acc[1][3] = mf(a1, b3[ks], acc[1][3]);
#pragma unroll
          for (int g = 0; g < 4; ++g) {
            acc[0][g] = mf(e0, ccur[g], acc[0][g]);
            acc[1][g] = mf(e1, ccur[g], acc[1][g]);
          }
        }
#pragma unroll
        for (int rt = 0; rt < 2; ++rt)
#pragma unroll
          for (int r = 0; r < 4; ++r)
            storeH(h0w, rt * 16 + hi * 4 + r, colb + lo,
                   cellup(acc[rt][0][r], acc[rt][1][r], acc[rt][2][r], acc[rt][3][r], c0s[rt][r]));
        dc0 ^= 1;
      }
      __syncthreads();
    }
  }
}

extern "C" void kernel_launch(void* const* d_in, const int* in_sizes, int n_in,
                              void* d_out, int out_size, void* d_ws, size_t ws_size,
                              hipStream_t stream) {
  (void)in_sizes; (void)n_in; (void)out_size; (void)ws_size;
  const float* x      = (const float*)d_in[0];
  // d_in[1] = target_len (60), hardcoded
  const float* eWih0  = (const float*)d_in[2];
  const float* eWhh0  = (const float*)d_in[3];
  const float* ebih0  = (const float*)d_in[4];
  const float* ebhh0  = (const float*)d_in[5];
  const float* eWih1  = (const float*)d_in[6];
  const float* eWhh1  = (const float*)d_in[7];
  const float* ebih1  = (const float*)d_in[8];
  const float* ebhh1  = (const float*)d_in[9];
  const float* dWih0  = (const float*)d_in[10];
  const float* dWhh0  = (const float*)d_in[11];
  const float* dbih0  = (const float*)d_in[12];
  const float* dbhh0  = (const float*)d_in[13];
  const float* dWih1  = (const float*)d_in[14];
  const float* dWhh1  = (const float*)d_in[15];
  const float* dbih1  = (const float*)d_in[16];
  const float* dbhh1  = (const float*)d_in[17];
  const float* fcW    = (const float*)d_in[18];
  const float* fcb    = (const float*)d_in[19];
  float* out          = (float*)d_out;
  char* ws            = (char*)d_ws;

  prep_kernel<<<280, 256, 0, stream>>>(eWih0, eWhh0, eWih1, eWhh1,
                                       dWih0, dWhh0, dWih1, dWhh1, fcW, ws);

  fused_kernel<<<256, 512, 0, stream>>>(
      x, ebih0, ebhh0, ebih1, ebhh1, dWih0, dbih0, dbhh0, dbih1, dbhh1,
      fcW, fcb, ws, out);
}

// Round 18
// 1050.659 us; speedup vs baseline: 1.6969x; 1.0972x over previous
//
#include <hip/hip_runtime.h>

// R16: persistent-register weight hoisting on R15 (1.15ms).
// Diagnosis: phases are ~12.5k cyc vs ~1k of pipe work; biggest component is
// L2 re-streaming of loop-invariant weight fragments (enc L1: 512B/thr/phase
// ~= 4.7k cyc/phase at ~56B/cyc/CU L2 BW). Fix: hoist half the fragments into
// persistent VGPRs (allocator is demand-driven; R15's 124 VGPR = demand):
//   - pwi[4][4] (64 reg): eWih1 frags for encoder; reloaded as dWih1 for dec.
//   - pb3[4]    (16 reg): W_hh0 gate-3 frags (eWhh0 enc / dWhh0 dec).
//   - streamed: eWhh1/dWhh1 + Wcomb, 2-deep pipelined, prefetched under the
//     persistent-MFMA block. Arithmetic order identical to R15.

using s16x8 = __attribute__((ext_vector_type(8))) short;
using h16x8 = __attribute__((ext_vector_type(8))) _Float16;
using f32x4 = __attribute__((ext_vector_type(4))) float;

#define DEV static __device__ __forceinline__

DEV unsigned short f2h(float f) {
  _Float16 h = (_Float16)f;  // RNE
  return __builtin_bit_cast(unsigned short, h);
}
DEV float h2f(short h) {
  return (float)__builtin_bit_cast(_Float16, (unsigned short)h);
}
DEV float rcp_(float x) { return __builtin_amdgcn_rcpf(x); }
DEV float sigm(float v) { return rcp_(1.0f + __expf(-v)); }
DEV float tanh_(float v) {  // 1 - 2/(e^{2v}+1)
  float e = __expf(2.0f * v);
  return 1.0f - 2.0f * rcp_(e + 1.0f);
}
DEV f32x4 mf(s16x8 a, s16x8 b, f32x4 c) {
  return __builtin_amdgcn_mfma_f32_16x16x32_f16(
      __builtin_bit_cast(h16x8, a), __builtin_bit_cast(h16x8, b), c, 0, 0, 0);
}
DEV f32x4 splat4(float v) { f32x4 r = {v, v, v, v}; return r; }

// [rows][128] fp16 buffer; 16 slots of 8 fp16 per row, XOR-swizzled.
DEV int swz(int row, int slot) { return row * 256 + (((slot ^ row) & 15) << 4); }
DEV s16x8 ldA(const char* buf, int rt, int ks, int lo, int hi) {
  return *(const s16x8*)(buf + swz(rt * 16 + lo, ks * 4 + hi));
}
DEV s16x8 ldB(const char* wlds, int colbase, int ks, int lo, int hi) {
  return *(const s16x8*)(wlds + swz(colbase + lo, ks * 4 + hi));
}
DEV void storeH(char* buf, int row, int col, unsigned short v) {
  int addr = row * 256 + ((((col >> 3) ^ row) & 15) << 4) + (col & 7) * 2;
  *(unsigned short*)(buf + addr) = v;
}
DEV unsigned short cellup(float gi, float gf, float gg, float go, float& c) {
  float i = sigm(gi), f = sigm(gf), g2 = tanh_(gg), o = sigm(go);
  c = f * c + i * g2;
  return f2h(o * tanh_(c));
}

// ---- d_ws layout (bytes) ----
// frag records, mats m*131072, addr = m*131072 + ks*32768 + col*64 + hi*16
//   m: 0=eWih1 1=eWhh1 2=dWih1 3=dWhh1 4=eWhh0 5=dWhh0 6=Wcomb(dWih0@fcW)
// WX (eWih0 K=16 zero-pad-32 frags) @917504 (32KB)
// IMG_E (eWhh0 rows 0..383 swizzled) @950272 (96KB)
// IMG_D (dWhh0 rows 0..383 swizzled) @1048576 (96KB)
#define WS_WX  917504
#define WS_IME 950272
#define WS_IMD 1048576

__global__ void prep_kernel(
    const float* __restrict__ eWih0, const float* __restrict__ eWhh0,
    const float* __restrict__ eWih1, const float* __restrict__ eWhh1,
    const float* __restrict__ dWih0, const float* __restrict__ dWhh0,
    const float* __restrict__ dWih1, const float* __restrict__ dWhh1,
    const float* __restrict__ fcW, char* __restrict__ ws) {
  int idx = blockIdx.x * 256 + threadIdx.x;
  if (idx < 57344) {  // 7 mats x 8192 fragment records
    int m = idx >> 13, r = idx & 8191;
    int col = r >> 4, ks = (r >> 2) & 3, hi = r & 3;
    s16x8 v;
    if (m == 6) {  // Wcomb[col][k] = dWih0[col][0]*fcW[0][k]+dWih0[col][1]*fcW[1][k]
      float w0 = dWih0[col * 2 + 0], w1 = dWih0[col * 2 + 1];
#pragma unroll
      for (int j = 0; j < 8; ++j) {
        int k = ks * 32 + hi * 8 + j;
        v[j] = (short)f2h(w0 * fcW[k] + w1 * fcW[128 + k]);
      }
    } else {
      const float* W;
      switch (m) {
        case 0: W = eWih1; break;
        case 1: W = eWhh1; break;
        case 2: W = dWih1; break;
        case 3: W = dWhh1; break;
        case 4: W = eWhh0; break;
        default: W = dWhh0; break;
      }
      const float* p = W + col * 128 + ks * 32 + hi * 8;
#pragma unroll
      for (int j = 0; j < 8; ++j) v[j] = (short)f2h(p[j]);
    }
    *(s16x8*)(ws + m * 131072 + ks * 32768 + col * 64 + hi * 16) = v;
  } else if (idx < 59392) {  // WX frags
    int r3 = idx - 57344;
    int col = r3 >> 2, hi = r3 & 3;
    s16x8 v;
#pragma unroll
    for (int j = 0; j < 8; ++j) v[j] = 0;
    if (hi < 2) {
      const float* p = eWih0 + col * 16 + hi * 8;
#pragma unroll
      for (int j = 0; j < 8; ++j) v[j] = (short)f2h(p[j]);
    }
    *(s16x8*)(ws + WS_WX + col * 64 + hi * 16) = v;
  } else if (idx < 71680) {  // swizzled 3-gate images (rows 0..383)
    int r2 = idx - 59392;
    int m = (r2 >= 6144), rr = m ? r2 - 6144 : r2;
    int row = rr >> 4, s = rr & 15;
    const float* p = (m ? dWhh0 : eWhh0) + row * 128 + s * 8;
    s16x8 v;
#pragma unroll
    for (int j = 0; j < 8; ++j) v[j] = (short)f2h(p[j]);
    *(s16x8*)(ws + (m ? WS_IMD : WS_IME) + row * 256 + (((s ^ row) & 15) << 4)) = v;
  }
}

__global__ __launch_bounds__(512, 2) void fused_kernel(
    const float* __restrict__ x,
    const float* __restrict__ ebih0, const float* __restrict__ ebhh0,
    const float* __restrict__ ebih1, const float* __restrict__ ebhh1,
    const float* __restrict__ dWih0,
    const float* __restrict__ dbih0, const float* __restrict__ dbhh0,
    const float* __restrict__ dbih1, const float* __restrict__ dbhh1,
    const float* __restrict__ fcW, const float* __restrict__ fcb,
    const char* __restrict__ ws, float* __restrict__ out) {
  __shared__ __align__(16) char smem[136960];
  char* wL   = smem;                       // 98304: 3-gate W_hh0 image
  char* h0B  = smem + 98304;               // 2 x 8192
  char* h1B  = smem + 114688;              // 2 x 8192
  char* xB   = smem + 131072;              // 2 x 2560
  float* inpL = (float*)(smem + 136192);   // 32x2 fp32 (decoder t=0 input)
  char* fcwL = smem + 136448;              // 2x128 fp16

  const int tid = threadIdx.x;
  const int w = tid >> 6, l = tid & 63, lo = l & 15, hi = l >> 4;
  const int row0 = blockIdx.x * 32;
  const int colb = w * 16;
  const int obase = (colb + lo) * 64 + hi * 16;   // frag offset, gate 0
  const int obase3 = obase + 384 * 64;            // gate 3

  // ================= init =================
  {  // stage IMG_E -> wL
    const int4* src = (const int4*)(ws + WS_IME);
    int4* dst = (int4*)wL;
    for (int i = tid; i < 6144; i += 512) dst[i] = src[i];
  }
  {  // zero h0B,h1B,xB
    int4 z = make_int4(0, 0, 0, 0);
    int4* p = (int4*)h0B;
    for (int i = tid; i < 2368; i += 512) p[i] = z;
  }

  float b0[4], b1[4];
  s16x8 wx0[4];
#pragma unroll
  for (int g = 0; g < 4; ++g) {
    int col = g * 128 + colb + lo;
    b0[g] = ebih0[col] + ebhh0[col];
    b1[g] = ebih1[col] + ebhh1[col];
    wx0[g] = *(const s16x8*)(ws + WS_WX + g * 8192 + obase);
  }
  // persistent weight fragments (loaded ONCE; reloaded at decoder switch)
  s16x8 pwi[4][4], pb3[4];
#pragma unroll
  for (int ks = 0; ks < 4; ++ks) {
#pragma unroll
    for (int g = 0; g < 4; ++g)
      pwi[ks][g] = *(const s16x8*)(ws + /*eWih1*/ ks * 32768 + g * 8192 + obase);
    pb3[ks] = *(const s16x8*)(ws + 4 * 131072 + ks * 32768 + obase3);  // eWhh0 g3
  }

  float c0s[2][4], c1s[2][4];
#pragma unroll
  for (int rt = 0; rt < 2; ++rt)
#pragma unroll
    for (int r = 0; r < 4; ++r) { c0s[rt][r] = 0.f; c1s[rt][r] = 0.f; }

  const int xr = tid >> 4, xf = tid & 15;
  const float* xrow = x + (long long)(row0 + xr) * 1600 + xf;
  *(unsigned short*)(xB + xr * 80 + xf * 2) = f2h(xrow[0]);  // x_0
  float xv = xrow[16];  // x_1
  int cur = 0;
  __syncthreads();

  // ================= encoder: 101 fused phases, 1 barrier each ============
  for (int k = 0; k <= 100; ++k) {
    char* h0r = h0B + cur * 8192;
    char* h0w = h0B + (cur ^ 1) * 8192;
    char* h1r = h1B + cur * 8192;
    char* h1w = h1B + (cur ^ 1) * 8192;
    char* xc  = xB + cur * 2560;
    char* xn  = xB + (cur ^ 1) * 2560;

    float xv_stage = xv;                       // x_{k+1}
    if (k < 98) xv = xrow[(k + 2) * 16];       // issue prefetch early

    if (k > 0) {  // ---- layer 1: h1(k) = cell1(h0(k)@eWih1 + h1(k-1)@eWhh1)
      f32x4 acc[2][4];
#pragma unroll
      for (int g = 0; g < 4; ++g) { acc[0][g] = splat4(b1[g]); acc[1][g] = splat4(b1[g]); }
      int lf = 0;
      asm("" : "+s"(lf));  // defeat LICM on the streamed half
      const char* W1h = ws + 131072 + lf;  // eWhh1 records
      // prefetch streamed groups ks=0,1 (land under the persistent MFMAs)
      s16x8 bf0[4], bf1[4];
#pragma unroll
      for (int g = 0; g < 4; ++g) {
        bf0[g] = *(const s16x8*)(W1h + 0 * 32768 + g * 8192 + obase);
        bf1[g] = *(const s16x8*)(W1h + 1 * 32768 + g * 8192 + obase);
      }
      // persistent half: A = h0(k), B = pwi (eWih1)
#pragma unroll
      for (int ks = 0; ks < 4; ++ks) {
        s16x8 a0 = ldA(h0r, 0, ks, lo, hi), a1 = ldA(h0r, 1, ks, lo, hi);
#pragma unroll
        for (int g = 0; g < 4; ++g) {
          acc[0][g] = mf(a0, pwi[ks][g], acc[0][g]);
          acc[1][g] = mf(a1, pwi[ks][g], acc[1][g]);
        }
      }
      // streamed half: A = h1(k-1), B = eWhh1, 2-deep pipeline
#pragma unroll
      for (int ks = 0; ks < 4; ++ks) {
        s16x8* bcur = (ks & 1) ? bf1 : bf0;
        if (ks < 2) {
          const char* wkn = W1h + (ks + 2) * 32768 + obase;
          s16x8* brel = (ks & 1) ? bf1 : bf0;  // reload the buffer being freed
          s16x8 tmp[4];
#pragma unroll
          for (int g = 0; g < 4; ++g) tmp[g] = *(const s16x8*)(wkn + g * 8192);
          s16x8 a0 = ldA(h1r, 0, ks, lo, hi), a1 = ldA(h1r, 1, ks, lo, hi);
#pragma unroll
          for (int g = 0; g < 4; ++g) {
            acc[0][g] = mf(a0, bcur[g], acc[0][g]);
            acc[1][g] = mf(a1, bcur[g], acc[1][g]);
          }
#pragma unroll
          for (int g = 0; g < 4; ++g) brel[g] = tmp[g];
        } else {
          s16x8 a0 = ldA(h1r, 0, ks, lo, hi), a1 = ldA(h1r, 1, ks, lo, hi);
#pragma unroll
          for (int g = 0; g < 4; ++g) {
            acc[0][g] = mf(a0, bcur[g], acc[0][g]);
            acc[1][g] = mf(a1, bcur[g], acc[1][g]);
          }
        }
      }
#pragma unroll
      for (int rt = 0; rt < 2; ++rt)
#pragma unroll
        for (int r = 0; r < 4; ++r)
          storeH(h1w, rt * 16 + hi * 4 + r, colb + lo,
                 cellup(acc[rt][0][r], acc[rt][1][r], acc[rt][2][r], acc[rt][3][r], c1s[rt][r]));
    }

    if (k < 100) {  // ---- layer 0: h0(k+1) = cell0(x_k, h0(k))
      f32x4 acc[2][4];
#pragma unroll
      for (int g = 0; g < 4; ++g) { acc[0][g] = splat4(b0[g]); acc[1][g] = splat4(b0[g]); }
      {
        s16x8 a0 = *(const s16x8*)(xc + lo * 80 + hi * 16);
        s16x8 a1 = *(const s16x8*)(xc + (16 + lo) * 80 + hi * 16);
#pragma unroll
        for (int g = 0; g < 4; ++g) {
          acc[0][g] = mf(a0, wx0[g], acc[0][g]);
          acc[1][g] = mf(a1, wx0[g], acc[1][g]);
        }
      }
#pragma unroll
      for (int ks = 0; ks < 4; ++ks) {
        s16x8 a0 = ldA(h0r, 0, ks, lo, hi), a1 = ldA(h0r, 1, ks, lo, hi);
#pragma unroll
        for (int g = 0; g < 3; ++g) {
          s16x8 bb = ldB(wL, g * 128 + colb, ks, lo, hi);
          acc[0][g] = mf(a0, bb, acc[0][g]);
          acc[1][g] = mf(a1, bb, acc[1][g]);
        }
        acc[0][3] = mf(a0, pb3[ks], acc[0][3]);
        acc[1][3] = mf(a1, pb3[ks], acc[1][3]);
      }
#pragma unroll
      for (int rt = 0; rt < 2; ++rt)
#pragma unroll
        for (int r = 0; r < 4; ++r)
          storeH(h0w, rt * 16 + hi * 4 + r, colb + lo,
                 cellup(acc[rt][0][r], acc[rt][1][r], acc[rt][2][r], acc[rt][3][r], c0s[rt][r]));
      if (k < 99)  // stage x_{k+1} for next phase
        *(unsigned short*)(xn + xr * 80 + xf * 2) = f2h(xv_stage);
    }
    __syncthreads();
    cur ^= 1;
  }
  // final states: h0(100) in h0B[cur^1], h1(100) in h1B[cur]
  int dc0 = cur ^ 1, dc1 = cur;

  // ================= restage for decoder =================
  {  // IMG_D -> wL
    const int4* src = (const int4*)(ws + WS_IMD);
    int4* dst = (int4*)wL;
    for (int i = tid; i < 6144; i += 512) dst[i] = src[i];
  }
  if (tid < 64) {  // dec_in = x[:, 99, :2]
    int r = tid >> 1, o = tid & 1;
    inpL[r * 2 + o] = x[(long long)(row0 + r) * 1600 + 1584 + o];
  }
  if (tid < 256) {
    int o = tid >> 7, k2 = tid & 127;
    *(unsigned short*)(fcwL + o * 256 + k2 * 2) = f2h(fcW[o * 128 + k2]);
  }
  // reload persistent frags for decoder: pwi = dWih1, pb3 = dWhh0 gate3
#pragma unroll
  for (int ks = 0; ks < 4; ++ks) {
#pragma unroll
    for (int g = 0; g < 4; ++g)
      pwi[ks][g] = *(const s16x8*)(ws + 2 * 131072 + ks * 32768 + g * 8192 + obase);
    pb3[ks] = *(const s16x8*)(ws + 5 * 131072 + ks * 32768 + obase3);
  }
  float dwx[4][2], b0f[4];
#pragma unroll
  for (int g = 0; g < 4; ++g) {
    int col = g * 128 + colb + lo;
    b0[g] = dbih0[col] + dbhh0[col];
    b1[g] = dbih1[col] + dbhh1[col];
    dwx[g][0] = dWih0[col * 2 + 0];
    dwx[g][1] = dWih0[col * 2 + 1];
  }
  float fb0 = fcb[0], fb1 = fcb[1];
#pragma unroll
  for (int g = 0; g < 4; ++g) b0f[g] = b0[g] + dwx[g][0] * fb0 + dwx[g][1] * fb1;
  __syncthreads();

  // ================= decoder =================
  // Phase A0 (t=0): h0^1 = cell0(inp0 [VALU], h0^0 @ dWhh0)
  {
    f32x4 acc[2][4];
    char* h0r = h0B + dc0 * 8192;
    char* h0w = h0B + (dc0 ^ 1) * 8192;
#pragma unroll
    for (int rt = 0; rt < 2; ++rt)
#pragma unroll
      for (int r = 0; r < 4; ++r) {
        float2 ip = *(const float2*)(inpL + (rt * 16 + hi * 4 + r) * 2);
#pragma unroll
        for (int g = 0; g < 4; ++g)
          acc[rt][g][r] = b0[g] + ip.x * dwx[g][0] + ip.y * dwx[g][1];
      }
#pragma unroll
    for (int ks = 0; ks < 4; ++ks) {
      s16x8 a0 = ldA(h0r, 0, ks, lo, hi), a1 = ldA(h0r, 1, ks, lo, hi);
#pragma unroll
      for (int g = 0; g < 3; ++g) {
        s16x8 bb = ldB(wL, g * 128 + colb, ks, lo, hi);
        acc[0][g] = mf(a0, bb, acc[0][g]);
        acc[1][g] = mf(a1, bb, acc[1][g]);
      }
      acc[0][3] = mf(a0, pb3[ks], acc[0][3]);
      acc[1][3] = mf(a1, pb3[ks], acc[1][3]);
    }
#pragma unroll
    for (int rt = 0; rt < 2; ++rt)
#pragma unroll
      for (int r = 0; r < 4; ++r)
        storeH(h0w, rt * 16 + hi * 4 + r, colb + lo,
               cellup(acc[rt][0][r], acc[rt][1][r], acc[rt][2][r], acc[rt][3][r], c0s[rt][r]));
    dc0 ^= 1;
    __syncthreads();
  }

  for (int t = 0; t < 60; ++t) {
    // ---- Phase B(t): h1^{t+1} = cell1(h0^{t+1} @ dWih1 + h1^t @ dWhh1)
    {
      char* h0r = h0B + dc0 * 8192;
      char* h1r = h1B + dc1 * 8192;
      char* h1w = h1B + (dc1 ^ 1) * 8192;
      f32x4 acc[2][4];
#pragma unroll
      for (int g = 0; g < 4; ++g) { acc[0][g] = splat4(b1[g]); acc[1][g] = splat4(b1[g]); }
      int lf = 0;
      asm("" : "+s"(lf));
      const char* WBh = ws + 3 * 131072 + lf;  // dWhh1 records
      s16x8 bf0[4], bf1[4];
#pragma unroll
      for (int g = 0; g < 4; ++g) {
        bf0[g] = *(const s16x8*)(WBh + 0 * 32768 + g * 8192 + obase);
        bf1[g] = *(const s16x8*)(WBh + 1 * 32768 + g * 8192 + obase);
      }
      // persistent half: A = h0^{t+1}, B = pwi (dWih1)
#pragma unroll
      for (int ks = 0; ks < 4; ++ks) {
        s16x8 a0 = ldA(h0r, 0, ks, lo, hi), a1 = ldA(h0r, 1, ks, lo, hi);
#pragma unroll
        for (int g = 0; g < 4; ++g) {
          acc[0][g] = mf(a0, pwi[ks][g], acc[0][g]);
          acc[1][g] = mf(a1, pwi[ks][g], acc[1][g]);
        }
      }
      // streamed half: A = h1^t, B = dWhh1, 2-deep
#pragma unroll
      for (int ks = 0; ks < 4; ++ks) {
        s16x8* bcur = (ks & 1) ? bf1 : bf0;
        if (ks < 2) {
          const char* wkn = WBh + (ks + 2) * 32768 + obase;
          s16x8* brel = (ks & 1) ? bf1 : bf0;
          s16x8 tmp[4];
#pragma unroll
          for (int g = 0; g < 4; ++g) tmp[g] = *(const s16x8*)(wkn + g * 8192);
          s16x8 a0 = ldA(h1r, 0, ks, lo, hi), a1 = ldA(h1r, 1, ks, lo, hi);
#pragma unroll
          for (int g = 0; g < 4; ++g) {
            acc[0][g] = mf(a0, bcur[g], acc[0][g]);
            acc[1][g] = mf(a1, bcur[g], acc[1][g]);
          }
#pragma unroll
          for (int g = 0; g < 4; ++g) brel[g] = tmp[g];
        } else {
          s16x8 a0 = ldA(h1r, 0, ks, lo, hi), a1 = ldA(h1r, 1, ks, lo, hi);
#pragma unroll
          for (int g = 0; g < 4; ++g) {
            acc[0][g] = mf(a0, bcur[g], acc[0][g]);
            acc[1][g] = mf(a1, bcur[g], acc[1][g]);
          }
        }
      }
#pragma unroll
      for (int rt = 0; rt < 2; ++rt)
#pragma unroll
        for (int r = 0; r < 4; ++r)
          storeH(h1w, rt * 16 + hi * 4 + r, colb + lo,
                 cellup(acc[rt][0][r], acc[rt][1][r], acc[rt][2][r], acc[rt][3][r], c1s[rt][r]));
      dc1 ^= 1;
      __syncthreads();
    }

    // ---- Phase A(t+1): FC out(t) (all waves) then
    //      h0^{t+2} = cell0'(h1^{t+1} @ Wcomb + h0^{t+1} @ dWhh0)
    {
      char* h1r = h1B + dc1 * 8192;   // h1^{t+1}
      {  // distributed FC: 64 sums (32 rows x 2 outs), 8 lanes x 2 slots each
        int rl = l >> 4, oo = (l >> 3) & 1, seg = l & 7;
        int row = w * 4 + rl;
        s16x8 hv0 = *(const s16x8*)(h1r + swz(row, seg));
        s16x8 wv0 = *(const s16x8*)(fcwL + oo * 256 + seg * 16);
        s16x8 hv1 = *(const s16x8*)(h1r + swz(row, seg + 8));
        s16x8 wv1 = *(const s16x8*)(fcwL + oo * 256 + (seg + 8) * 16);
        float sum = 0.f;
#pragma unroll
        for (int j = 0; j < 8; ++j)
          sum += h2f(hv0[j]) * h2f(wv0[j]) + h2f(hv1[j]) * h2f(wv1[j]);
        sum += __shfl_xor(sum, 1);
        sum += __shfl_xor(sum, 2);
        sum += __shfl_xor(sum, 4);
        if (seg == 0)
          out[((long long)(row0 + row) * 60 + t) * 2 + oo] = sum + (oo ? fb1 : fb0);
      }
      if (t < 59) {
        char* h0r = h0B + dc0 * 8192;
        char* h0w = h0B + (dc0 ^ 1) * 8192;
        f32x4 acc[2][4];
#pragma unroll
        for (int g = 0; g < 4; ++g) { acc[0][g] = splat4(b0f[g]); acc[1][g] = splat4(b0f[g]); }
        int lf = 0;
        asm("" : "+s"(lf));
        const char* WC = ws + 6 * 131072 + lf;   // Wcomb records
        s16x8 cf0[4], cf1[4];
#pragma unroll
        for (int g = 0; g < 4; ++g) {
          cf0[g] = *(const s16x8*)(WC + 0 * 32768 + g * 8192 + obase);
          cf1[g] = *(const s16x8*)(WC + 1 * 32768 + g * 8192 + obase);
        }
#pragma unroll
        for (int ks = 0; ks < 4; ++ks) {
          s16x8* ccur = (ks & 1) ? cf1 : cf0;
          s16x8 tmp[4];
          if (ks < 2) {
            const char* wkn = WC + (ks + 2) * 32768 + obase;
#pragma unroll
            for (int g = 0; g < 4; ++g) tmp[g] = *(const s16x8*)(wkn + g * 8192);
          }
          s16x8 a0 = ldA(h0r, 0, ks, lo, hi), a1 = ldA(h0r, 1, ks, lo, hi);
          s16x8 e0 = ldA(h1r, 0, ks, lo, hi), e1 = ldA(h1r, 1, ks, lo, hi);
#pragma unroll
          for (int g = 0; g < 3; ++g) {
            s16x8 bb = ldB(wL, g * 128 + colb, ks, lo, hi);
            acc[0][g] = mf(a0, bb, acc[0][g]);
            acc[1][g] = mf(a1, bb, acc[1][g]);
          }
          acc[0][3] = mf(a0, pb3[ks], acc[0][3]);
          acc[1][3] = mf(a1, pb3[ks], acc[1][3]);
#pragma unroll
          for (int g = 0; g < 4; ++g) {
            acc[0][g] = mf(e0, ccur[g], acc[0][g]);
            acc[1][g] = mf(e1, ccur[g], acc[1][g]);
          }
          if (ks < 2) {
            s16x8* crel = (ks & 1) ? cf1 : cf0;
#pragma unroll
            for (int g = 0; g < 4; ++g) crel[g] = tmp[g];
          }
        }
#pragma unroll
        for (int rt = 0; rt < 2; ++rt)
#pragma unroll
          for (int r = 0; r < 4; ++r)
            storeH(h0w, rt * 16 + hi * 4 + r, colb + lo,
                   cellup(acc[rt][0][r], acc[rt][1][r], acc[rt][2][r], acc[rt][3][r], c0s[rt][r]));
        dc0 ^= 1;
      }
      __syncthreads();
    }
  }
}

extern "C" void kernel_launch(void* const* d_in, const int* in_sizes, int n_in,
                              void* d_out, int out_size, void* d_ws, size_t ws_size,
                              hipStream_t stream) {
  (void)in_sizes; (void)n_in; (void)out_size; (void)ws_size;
  const float* x      = (const float*)d_in[0];
  // d_in[1] = target_len (60), hardcoded
  const float* eWih0  = (const float*)d_in[2];
  const float* eWhh0  = (const float*)d_in[3];
  const float* ebih0  = (const float*)d_in[4];
  const float* ebhh0  = (const float*)d_in[5];
  const float* eWih1  = (const float*)d_in[6];
  const float* eWhh1  = (const float*)d_in[7];
  const float* ebih1  = (const float*)d_in[8];
  const float* ebhh1  = (const float*)d_in[9];
  const float* dWih0  = (const float*)d_in[10];
  const float* dWhh0  = (const float*)d_in[11];
  const float* dbih0  = (const float*)d_in[12];
  const float* dbhh0  = (const float*)d_in[13];
  const float* dWih1  = (const float*)d_in[14];
  const float* dWhh1  = (const float*)d_in[15];
  const float* dbih1  = (const float*)d_in[16];
  const float* dbhh1  = (const float*)d_in[17];
  const float* fcW    = (const float*)d_in[18];
  const float* fcb    = (const float*)d_in[19];
  float* out          = (float*)d_out;
  char* ws            = (char*)d_ws;

  prep_kernel<<<280, 256, 0, stream>>>(eWih0, eWhh0, eWih1, eWhh1,
                                       dWih0, dWhh0, dWih1, dWhh1, fcW, ws);

  fused_kernel<<<256, 512, 0, stream>>>(
      x, ebih0, ebhh0, ebih1, ebhh1, dWih0, dbih0, dbhh0, dbih1, dbhh1,
      fcW, fcb, ws, out);
}